// Round 1
// baseline (708.450 us; speedup 1.0000x reference)
//
#include <hip/hip_runtime.h>

constexpr int Bn  = 4;
constexpr int Sn  = 1024;
constexpr int Dn  = 1024;
constexpr int Hn  = 16;
constexpr int HDn = 64;
constexpr float NEGV = -10000000.0f;

__device__ __forceinline__ void fma4x4(float (&acc)[4][4], const float4 a, const float4 b) {
    const float av[4] = {a.x, a.y, a.z, a.w};
    const float bv[4] = {b.x, b.y, b.z, b.w};
#pragma unroll
    for (int i = 0; i < 4; ++i)
#pragma unroll
        for (int j = 0; j < 4; ++j)
            acc[i][j] = fmaf(av[i], bv[j], acc[i][j]);
}

// ---------------------------------------------------------------------------
// QKV projection: Out[b,h,s,hd] = x[b,s,:] @ W[:, h*64+hd] + bias
// grid: (Hn=16 col-tiles, 64 row-tiles, 3 {Q,K,V}), block: 256
// ---------------------------------------------------------------------------
__global__ __launch_bounds__(256) void qkv_proj(
    const float* __restrict__ x,
    const float* __restrict__ Wq, const float* __restrict__ bq,
    const float* __restrict__ Wk, const float* __restrict__ bk,
    const float* __restrict__ Wv, const float* __restrict__ bv,
    float* __restrict__ Qo, float* __restrict__ Ko, float* __restrict__ Vo)
{
    const int which = blockIdx.z;
    const float* __restrict__ W    = (which == 0) ? Wq : (which == 1) ? Wk : Wv;
    const float* __restrict__ bias = (which == 0) ? bq : (which == 1) ? bk : bv;
    float* __restrict__ Out        = (which == 0) ? Qo : (which == 1) ? Ko : Vo;

    const int m0 = blockIdx.y * 64;
    const int h  = blockIdx.x;       // one 64-col tile == one head
    const int n0 = h * 64;
    const int t  = threadIdx.x;

    // K-major tiles, stride 68 floats (272 B: 16B-aligned rows, conflict-breaking pad)
    __shared__ __align__(16) float At[16][68];  // At[k][m]
    __shared__ __align__(16) float Bs[16][68];  // Bs[k][n]

    const int r0 = (t >> 4) * 4;     // 0..60 output rows (within tile)
    const int c0 = (t & 15) * 4;     // 0..60 output cols

    const int xrow = t >> 2;         // 0..63  (x-tile load)
    const int xk4  = (t & 3) * 4;    // 0..12
    const int wk   = t >> 4;         // 0..15  (W-tile load)
    const int wn4  = (t & 15) * 4;   // 0..60

    float acc[4][4] = {};

    for (int k0 = 0; k0 < Dn; k0 += 16) {
        __syncthreads();
        float4 xa = *(const float4*)&x[(size_t)(m0 + xrow) * Dn + k0 + xk4];
        At[xk4 + 0][xrow] = xa.x;
        At[xk4 + 1][xrow] = xa.y;
        At[xk4 + 2][xrow] = xa.z;
        At[xk4 + 3][xrow] = xa.w;
        *(float4*)&Bs[wk][wn4] = *(const float4*)&W[(size_t)(k0 + wk) * Dn + n0 + wn4];
        __syncthreads();
#pragma unroll
        for (int kk = 0; kk < 16; ++kk) {
            float4 a = *(const float4*)&At[kk][r0];
            float4 b = *(const float4*)&Bs[kk][c0];
            fma4x4(acc, a, b);
        }
    }

    const float4 bv4 = *(const float4*)&bias[n0 + c0];
    const float bb[4] = {bv4.x, bv4.y, bv4.z, bv4.w};
#pragma unroll
    for (int i = 0; i < 4; ++i) {
        const int m = m0 + r0 + i;
        const int b = m >> 10;       // batch
        const int s = m & 1023;      // seq pos
        float4 o;
        o.x = acc[i][0] + bb[0];
        o.y = acc[i][1] + bb[1];
        o.z = acc[i][2] + bb[2];
        o.w = acc[i][3] + bb[3];
        *(float4*)&Out[(((size_t)(b * Hn + h)) * Sn + s) * HDn + c0] = o;
    }
}

// ---------------------------------------------------------------------------
// Flash-style attention + relu. grid: (16 q-tiles, 16 heads, 4 batch), block 256.
// Each thread: 4 q-rows x 4 cols of the 64x64 score tile; 16-lane groups own a
// row-quad and reduce max/sum via shfl_xor. Kt storage is reused for P.
// ---------------------------------------------------------------------------
__global__ __launch_bounds__(256) void attn(
    const float* __restrict__ Q, const float* __restrict__ K, const float* __restrict__ V,
    const float* __restrict__ adj, float* __restrict__ out)
{
    const int qt = blockIdx.x;
    const int h  = blockIdx.y;
    const int b  = blockIdx.z;
    const int t  = threadIdx.x;
    const int q0 = qt * 64;

    const size_t hb = ((size_t)(b * Hn + h)) * Sn * HDn;

    __shared__ __align__(16) float Qt[64][68];  // Qt[d][row]
    __shared__ __align__(16) float Kt[64][68];  // Kt[d][col]; reused as Pt[col][row]
    __shared__ __align__(16) float Vs[64][68];  // Vs[col][d]

    const int lrow = t >> 2;          // 0..63
    const int ld0  = (t & 3) * 16;    // 0,16,32,48

#pragma unroll
    for (int j = 0; j < 4; ++j) {
        float4 qv = *(const float4*)&Q[hb + (size_t)(q0 + lrow) * HDn + ld0 + j * 4];
        Qt[ld0 + j * 4 + 0][lrow] = qv.x;
        Qt[ld0 + j * 4 + 1][lrow] = qv.y;
        Qt[ld0 + j * 4 + 2][lrow] = qv.z;
        Qt[ld0 + j * 4 + 3][lrow] = qv.w;
    }

    const int r0 = (t >> 4) * 4;
    const int c0 = (t & 15) * 4;

    float m_i[4] = {-3.0e38f, -3.0e38f, -3.0e38f, -3.0e38f};
    float l_i[4] = {0.f, 0.f, 0.f, 0.f};
    float acc[4][4] = {};

    for (int kt = 0; kt < 16; ++kt) {
        __syncthreads();  // prior-iter Kt(P)/Vs reads complete
#pragma unroll
        for (int j = 0; j < 4; ++j) {
            float4 kv = *(const float4*)&K[hb + (size_t)(kt * 64 + lrow) * HDn + ld0 + j * 4];
            Kt[ld0 + j * 4 + 0][lrow] = kv.x;
            Kt[ld0 + j * 4 + 1][lrow] = kv.y;
            Kt[ld0 + j * 4 + 2][lrow] = kv.z;
            Kt[ld0 + j * 4 + 3][lrow] = kv.w;
            *(float4*)&Vs[lrow][ld0 + j * 4] =
                *(const float4*)&V[hb + (size_t)(kt * 64 + lrow) * HDn + ld0 + j * 4];
        }
        __syncthreads();

        // scores: s[i][j] = q[r0+i] . k[c0+j]
        float s[4][4] = {};
#pragma unroll
        for (int d = 0; d < 64; ++d) {
            float4 a  = *(const float4*)&Qt[d][r0];
            float4 bk = *(const float4*)&Kt[d][c0];
            fma4x4(s, a, bk);
        }

        // scale + adjacency mask
#pragma unroll
        for (int i = 0; i < 4; ++i) {
            const float4 am = *(const float4*)&adj[((size_t)b * Sn + (q0 + r0 + i)) * Sn + kt * 64 + c0];
            const float av[4] = {am.x, am.y, am.z, am.w};
#pragma unroll
            for (int j = 0; j < 4; ++j)
                s[i][j] = s[i][j] * 0.125f + (av[j] < 0.5f ? NEGV : 0.0f);
        }

        // row max across the 16-lane group
        float mt[4];
#pragma unroll
        for (int i = 0; i < 4; ++i)
            mt[i] = fmaxf(fmaxf(s[i][0], s[i][1]), fmaxf(s[i][2], s[i][3]));
#pragma unroll
        for (int off = 1; off < 16; off <<= 1)
#pragma unroll
            for (int i = 0; i < 4; ++i)
                mt[i] = fmaxf(mt[i], __shfl_xor(mt[i], off, 64));

        float p[4][4], rs[4], mnew[4], alpha[4];
#pragma unroll
        for (int i = 0; i < 4; ++i) {
            mnew[i]  = fmaxf(m_i[i], mt[i]);
            alpha[i] = __expf(m_i[i] - mnew[i]);
            rs[i] = 0.f;
#pragma unroll
            for (int j = 0; j < 4; ++j) {
                p[i][j] = __expf(s[i][j] - mnew[i]);
                rs[i] += p[i][j];
            }
        }
#pragma unroll
        for (int off = 1; off < 16; off <<= 1)
#pragma unroll
            for (int i = 0; i < 4; ++i)
                rs[i] += __shfl_xor(rs[i], off, 64);
#pragma unroll
        for (int i = 0; i < 4; ++i) {
            l_i[i] = l_i[i] * alpha[i] + rs[i];
            m_i[i] = mnew[i];
#pragma unroll
            for (int j = 0; j < 4; ++j)
                acc[i][j] *= alpha[i];
        }

        __syncthreads();  // all lanes done reading Kt as K
        // store P transposed into Kt storage: Pt[col][row]
#pragma unroll
        for (int i = 0; i < 4; ++i)
#pragma unroll
            for (int j = 0; j < 4; ++j)
                Kt[c0 + j][r0 + i] = p[i][j];
        __syncthreads();

        // acc[i][j] += sum_c P[r0+i][c] * V[c][c0+j]   (c0 reused as dim offset)
#pragma unroll
        for (int c = 0; c < 64; ++c) {
            float4 p4 = *(const float4*)&Kt[c][r0];
            float4 v4 = *(const float4*)&Vs[c][c0];
            fma4x4(acc, p4, v4);
        }
    }

    // epilogue: relu(acc / l) -> out[b, q0+r0+i, h*64 + c0 + j]
#pragma unroll
    for (int i = 0; i < 4; ++i) {
        const float inv = 1.0f / l_i[i];
        float4 o;
        o.x = fmaxf(acc[i][0] * inv, 0.0f);
        o.y = fmaxf(acc[i][1] * inv, 0.0f);
        o.z = fmaxf(acc[i][2] * inv, 0.0f);
        o.w = fmaxf(acc[i][3] * inv, 0.0f);
        *(float4*)&out[((size_t)b * Sn + (q0 + r0 + i)) * Dn + h * HDn + c0] = o;
    }
}

extern "C" void kernel_launch(void* const* d_in, const int* in_sizes, int n_in,
                              void* d_out, int out_size, void* d_ws, size_t ws_size,
                              hipStream_t stream)
{
    const float* x   = (const float*)d_in[0];
    const float* adj = (const float*)d_in[1];
    const float* Wq  = (const float*)d_in[2];
    const float* bq  = (const float*)d_in[3];
    const float* Wk  = (const float*)d_in[4];
    const float* bk  = (const float*)d_in[5];
    const float* Wv  = (const float*)d_in[6];
    const float* bv  = (const float*)d_in[7];
    float* out = (float*)d_out;

    const size_t qkv_elems = (size_t)Bn * Hn * Sn * HDn;  // 4,194,304
    float* Qw = (float*)d_ws;
    float* Kw = Qw + qkv_elems;
    float* Vw = Kw + qkv_elems;

    qkv_proj<<<dim3(Hn, (Bn * Sn) / 64, 3), 256, 0, stream>>>(
        x, Wq, bq, Wk, bk, Wv, bv, Qw, Kw, Vw);

    attn<<<dim3(Sn / 64, Hn, Bn), 256, 0, stream>>>(Qw, Kw, Vw, adj, out);

    // Output 1: adj passthrough
    hipMemcpyAsync(out + (size_t)Bn * Sn * Dn, adj,
                   (size_t)Bn * Sn * Sn * sizeof(float),
                   hipMemcpyDeviceToDevice, stream);
}

// Round 2
// 418.064 us; speedup vs baseline: 1.6946x; 1.6946x over previous
//
#include <hip/hip_runtime.h>

constexpr int Bn  = 4;
constexpr int Sn  = 1024;
constexpr int Dn  = 1024;
constexpr int Hn  = 16;
constexpr int HDn = 64;
constexpr float NEGV = -10000000.0f;

using short8  = __attribute__((ext_vector_type(8))) short;
using float4v = __attribute__((ext_vector_type(4))) float;

__device__ __forceinline__ ushort f2bf(float f) {
    union { float f; unsigned u; } v; v.f = f;
    unsigned r = v.u + 0x7fff + ((v.u >> 16) & 1);   // RNE
    return (ushort)(r >> 16);
}
__device__ __forceinline__ float bf_lo(unsigned u) { return __uint_as_float(u << 16); }
__device__ __forceinline__ float bf_hi(unsigned u) { return __uint_as_float(u & 0xffff0000u); }

__device__ __forceinline__ void gload16(const void* g, void* l) {
    __builtin_amdgcn_global_load_lds(
        (const __attribute__((address_space(1))) void*)g,
        (__attribute__((address_space(3))) void*)l, 16, 0, 0);
}

__device__ __forceinline__ void fma4x4(float (&acc)[4][4], const float4 a, const float4 b) {
    const float av[4] = {a.x, a.y, a.z, a.w};
    const float bv[4] = {b.x, b.y, b.z, b.w};
#pragma unroll
    for (int i = 0; i < 4; ++i)
#pragma unroll
        for (int j = 0; j < 4; ++j)
            acc[i][j] = fmaf(av[i], bv[j], acc[i][j]);
}

// ---------------------------------------------------------------------------
// x (fp32, 4096x1024) -> xb (bf16 row-major). 8 floats/thread.
// ---------------------------------------------------------------------------
__global__ __launch_bounds__(256) void convert_x(const float* __restrict__ x,
                                                 ushort* __restrict__ xb)
{
    const size_t i = ((size_t)blockIdx.x * 256 + threadIdx.x) * 8;
    float4 a = *(const float4*)&x[i];
    float4 b = *(const float4*)&x[i + 4];
    ushort o[8] = {f2bf(a.x), f2bf(a.y), f2bf(a.z), f2bf(a.w),
                   f2bf(b.x), f2bf(b.y), f2bf(b.z), f2bf(b.w)};
    *(uint4*)&xb[i] = *(const uint4*)o;
}

// ---------------------------------------------------------------------------
// W[which] (K x N fp32 row-major) -> Wt (N x K bf16 row-major), 64x64 tiles.
// grid (16 kblk, 16 nblk, 3)
// ---------------------------------------------------------------------------
__global__ __launch_bounds__(256) void transpose_w(
    const float* __restrict__ Wq, const float* __restrict__ Wk,
    const float* __restrict__ Wv, ushort* __restrict__ Wt)
{
    const int which = blockIdx.z;
    const float* __restrict__ W = (which == 0) ? Wq : (which == 1) ? Wk : Wv;
    ushort* __restrict__ O = Wt + (size_t)which * Dn * Dn;

    const int k0 = blockIdx.x * 64;
    const int n0 = blockIdx.y * 64;
    const int t  = threadIdx.x;

    __shared__ __align__(16) ushort T[64][72];   // T[n][k]

    const int kl = t >> 4;            // 0..15
    const int nl = (t & 15) * 4;      // 0..60
#pragma unroll
    for (int p = 0; p < 4; ++p) {
        float4 w = *(const float4*)&W[(size_t)(k0 + p * 16 + kl) * Dn + n0 + nl];
        T[nl + 0][p * 16 + kl] = f2bf(w.x);
        T[nl + 1][p * 16 + kl] = f2bf(w.y);
        T[nl + 2][p * 16 + kl] = f2bf(w.z);
        T[nl + 3][p * 16 + kl] = f2bf(w.w);
    }
    __syncthreads();
    const int nr = t >> 2;            // 0..63
    const int kc = (t & 3) * 16;      // 0,16,32,48
    uint4 u0 = *(const uint4*)&T[nr][kc];
    uint4 u1 = *(const uint4*)&T[nr][kc + 8];
    *(uint4*)&O[(size_t)(n0 + nr) * Dn + k0 + kc]     = u0;
    *(uint4*)&O[(size_t)(n0 + nr) * Dn + k0 + kc + 8] = u1;
}

// ---------------------------------------------------------------------------
// bf16 MFMA GEMM (m97-style): Out = xb @ Wt^T + bias, Out in [B,H,S,HD] bf16.
// 128x128 tile, 4 waves, 4x4 mfma_f32_16x16x32_bf16 per wave, BK=32.
// grid (8 n-tiles, 32 m-tiles, 3 {Q,K,V})
// ---------------------------------------------------------------------------
__global__ __launch_bounds__(256) void qkv_gemm(
    const ushort* __restrict__ xb, const ushort* __restrict__ Wt,
    const float* __restrict__ bq, const float* __restrict__ bk,
    const float* __restrict__ bv,
    ushort* __restrict__ Qb, ushort* __restrict__ Kb, ushort* __restrict__ Vb)
{
    const int which = blockIdx.z;
    const ushort* __restrict__ Bw   = Wt + (size_t)which * Dn * Dn;
    const float* __restrict__  bias = (which == 0) ? bq : (which == 1) ? bk : bv;
    ushort* __restrict__       Out  = (which == 0) ? Qb : (which == 1) ? Kb : Vb;

    const int n0   = blockIdx.x * 128;
    const int m0   = blockIdx.y * 128;
    const int tid  = threadIdx.x;
    const int wave = tid >> 6;
    const int lane = tid & 63;
    const int wm   = wave >> 1;       // 0..1
    const int wn   = wave & 1;        // 0..1

    __shared__ __align__(16) ushort As[128 * 32];   // As[m*32 + k]
    __shared__ __align__(16) ushort Bs[128 * 32];   // Bs[n*32 + k]

    // staging: chunk L = wave*64+lane (+256), holds 8 elems at row L>>2, k-off (L&3)*8
    const int L0 = wave * 64 + lane;
    const int r0s = L0 >> 2, c0s = (L0 & 3) * 8;
    const int L1 = L0 + 256;
    const int r1s = L1 >> 2, c1s = (L1 & 3) * 8;

    const ushort* pA0 = &xb[(size_t)(m0 + r0s) * Dn + c0s];
    const ushort* pA1 = &xb[(size_t)(m0 + r1s) * Dn + c1s];
    const ushort* pB0 = &Bw[(size_t)(n0 + r0s) * Dn + c0s];
    const ushort* pB1 = &Bw[(size_t)(n0 + r1s) * Dn + c1s];

    char* ldsA0 = (char*)As + wave * 1024;
    char* ldsA1 = (char*)As + wave * 1024 + 4096;
    char* ldsB0 = (char*)Bs + wave * 1024;
    char* ldsB1 = (char*)Bs + wave * 1024 + 4096;

    const int mlane = lane & 15;
    const int kg    = (lane >> 4) * 8;

    float4v acc[4][4];
    const float4v z4 = {0.f, 0.f, 0.f, 0.f};
#pragma unroll
    for (int i = 0; i < 4; ++i)
#pragma unroll
        for (int j = 0; j < 4; ++j) acc[i][j] = z4;

    for (int k0 = 0; k0 < Dn; k0 += 32) {
        __syncthreads();
        gload16(pA0, ldsA0);
        gload16(pA1, ldsA1);
        gload16(pB0, ldsB0);
        gload16(pB1, ldsB1);
        pA0 += 32; pA1 += 32; pB0 += 32; pB1 += 32;
        __syncthreads();

        short8 af[4], bf[4];
#pragma unroll
        for (int i = 0; i < 4; ++i)
            af[i] = *(const short8*)&As[(wm * 64 + i * 16 + mlane) * 32 + kg];
#pragma unroll
        for (int j = 0; j < 4; ++j)
            bf[j] = *(const short8*)&Bs[(wn * 64 + j * 16 + mlane) * 32 + kg];
#pragma unroll
        for (int i = 0; i < 4; ++i)
#pragma unroll
            for (int j = 0; j < 4; ++j)
                acc[i][j] = __builtin_amdgcn_mfma_f32_16x16x32_bf16(af[i], bf[j], acc[i][j], 0, 0, 0);
    }

    // epilogue: +bias, bf16, scatter to [B,H,S,HD]
    const int rb  = (lane >> 4) * 4;   // D row base
    const int col = lane & 15;         // D col
#pragma unroll
    for (int j = 0; j < 4; ++j) {
        const int n  = n0 + wn * 64 + j * 16 + col;
        const float bias_n = bias[n];
        const int h  = n >> 6;
        const int hd = n & 63;
#pragma unroll
        for (int i = 0; i < 4; ++i) {
#pragma unroll
            for (int r = 0; r < 4; ++r) {
                const int m = m0 + wm * 64 + i * 16 + rb + r;
                const int b = m >> 10;
                const int s = m & 1023;
                Out[(((size_t)(b * Hn + h)) * Sn + s) * HDn + hd] = f2bf(acc[i][j][r] + bias_n);
            }
        }
    }
}

// ---------------------------------------------------------------------------
// Flash-style attention + relu (fp32 compute, bf16 Q/K/V input).
// grid: (16 q-tiles, 16 heads, 4 batch), block 256.
// ---------------------------------------------------------------------------
__global__ __launch_bounds__(256) void attn(
    const ushort* __restrict__ Q, const ushort* __restrict__ K,
    const ushort* __restrict__ V,
    const float* __restrict__ adj, float* __restrict__ out)
{
    const int qt = blockIdx.x;
    const int h  = blockIdx.y;
    const int b  = blockIdx.z;
    const int t  = threadIdx.x;
    const int q0 = qt * 64;

    const size_t hb = ((size_t)(b * Hn + h)) * Sn * HDn;

    __shared__ __align__(16) float Qt[64][68];  // Qt[d][row]
    __shared__ __align__(16) float Kt[64][68];  // Kt[d][col]; reused as Pt[col][row]
    __shared__ __align__(16) float Vs[64][68];  // Vs[col][d]

    const int lrow = t >> 2;          // 0..63
    const int ld0  = (t & 3) * 16;    // 0,16,32,48

#pragma unroll
    for (int j = 0; j < 2; ++j) {
        uint4 u = *(const uint4*)&Q[hb + (size_t)(q0 + lrow) * HDn + ld0 + j * 8];
        const int d = ld0 + j * 8;
        Qt[d + 0][lrow] = bf_lo(u.x); Qt[d + 1][lrow] = bf_hi(u.x);
        Qt[d + 2][lrow] = bf_lo(u.y); Qt[d + 3][lrow] = bf_hi(u.y);
        Qt[d + 4][lrow] = bf_lo(u.z); Qt[d + 5][lrow] = bf_hi(u.z);
        Qt[d + 6][lrow] = bf_lo(u.w); Qt[d + 7][lrow] = bf_hi(u.w);
    }

    const int r0 = (t >> 4) * 4;
    const int c0 = (t & 15) * 4;

    float m_i[4] = {-3.0e38f, -3.0e38f, -3.0e38f, -3.0e38f};
    float l_i[4] = {0.f, 0.f, 0.f, 0.f};
    float acc[4][4] = {};

    for (int kt = 0; kt < 16; ++kt) {
        __syncthreads();  // prior-iter Kt(P)/Vs reads complete
#pragma unroll
        for (int j = 0; j < 2; ++j) {
            const int d = ld0 + j * 8;
            uint4 uk = *(const uint4*)&K[hb + (size_t)(kt * 64 + lrow) * HDn + d];
            Kt[d + 0][lrow] = bf_lo(uk.x); Kt[d + 1][lrow] = bf_hi(uk.x);
            Kt[d + 2][lrow] = bf_lo(uk.y); Kt[d + 3][lrow] = bf_hi(uk.y);
            Kt[d + 4][lrow] = bf_lo(uk.z); Kt[d + 5][lrow] = bf_hi(uk.z);
            Kt[d + 6][lrow] = bf_lo(uk.w); Kt[d + 7][lrow] = bf_hi(uk.w);
            uint4 uv = *(const uint4*)&V[hb + (size_t)(kt * 64 + lrow) * HDn + d];
            float* vp = &Vs[lrow][d];
            vp[0] = bf_lo(uv.x); vp[1] = bf_hi(uv.x);
            vp[2] = bf_lo(uv.y); vp[3] = bf_hi(uv.y);
            vp[4] = bf_lo(uv.z); vp[5] = bf_hi(uv.z);
            vp[6] = bf_lo(uv.w); vp[7] = bf_hi(uv.w);
        }
        __syncthreads();

        // scores: s[i][j] = q[r0+i] . k[c0+j]
        float s[4][4] = {};
#pragma unroll
        for (int d = 0; d < 64; ++d) {
            float4 a  = *(const float4*)&Qt[d][r0];
            float4 bk = *(const float4*)&Kt[d][c0];
            fma4x4(s, a, bk);
        }

        // scale + adjacency mask
#pragma unroll
        for (int i = 0; i < 4; ++i) {
            const float4 am = *(const float4*)&adj[((size_t)b * Sn + (q0 + r0 + i)) * Sn + kt * 64 + c0];
            const float av[4] = {am.x, am.y, am.z, am.w};
#pragma unroll
            for (int j = 0; j < 4; ++j)
                s[i][j] = s[i][j] * 0.125f + (av[j] < 0.5f ? NEGV : 0.0f);
        }

        // row max across the 16-lane group
        float mt[4];
#pragma unroll
        for (int i = 0; i < 4; ++i)
            mt[i] = fmaxf(fmaxf(s[i][0], s[i][1]), fmaxf(s[i][2], s[i][3]));
#pragma unroll
        for (int off = 1; off < 16; off <<= 1)
#pragma unroll
            for (int i = 0; i < 4; ++i)
                mt[i] = fmaxf(mt[i], __shfl_xor(mt[i], off, 64));

        float p[4][4], rs[4], mnew[4], alpha[4];
#pragma unroll
        for (int i = 0; i < 4; ++i) {
            mnew[i]  = fmaxf(m_i[i], mt[i]);
            alpha[i] = __expf(m_i[i] - mnew[i]);
            rs[i] = 0.f;
#pragma unroll
            for (int j = 0; j < 4; ++j) {
                p[i][j] = __expf(s[i][j] - mnew[i]);
                rs[i] += p[i][j];
            }
        }
#pragma unroll
        for (int off = 1; off < 16; off <<= 1)
#pragma unroll
            for (int i = 0; i < 4; ++i)
                rs[i] += __shfl_xor(rs[i], off, 64);
#pragma unroll
        for (int i = 0; i < 4; ++i) {
            l_i[i] = l_i[i] * alpha[i] + rs[i];
            m_i[i] = mnew[i];
#pragma unroll
            for (int j = 0; j < 4; ++j)
                acc[i][j] *= alpha[i];
        }

        __syncthreads();  // all lanes done reading Kt as K
#pragma unroll
        for (int i = 0; i < 4; ++i)
#pragma unroll
            for (int j = 0; j < 4; ++j)
                Kt[c0 + j][r0 + i] = p[i][j];
        __syncthreads();

#pragma unroll
        for (int c = 0; c < 64; ++c) {
            float4 p4 = *(const float4*)&Kt[c][r0];
            float4 v4 = *(const float4*)&Vs[c][c0];
            fma4x4(acc, p4, v4);
        }
    }

#pragma unroll
    for (int i = 0; i < 4; ++i) {
        const float inv = 1.0f / l_i[i];
        float4 o;
        o.x = fmaxf(acc[i][0] * inv, 0.0f);
        o.y = fmaxf(acc[i][1] * inv, 0.0f);
        o.z = fmaxf(acc[i][2] * inv, 0.0f);
        o.w = fmaxf(acc[i][3] * inv, 0.0f);
        *(float4*)&out[((size_t)b * Sn + (q0 + r0 + i)) * Dn + h * HDn + c0] = o;
    }
}

extern "C" void kernel_launch(void* const* d_in, const int* in_sizes, int n_in,
                              void* d_out, int out_size, void* d_ws, size_t ws_size,
                              hipStream_t stream)
{
    const float* x   = (const float*)d_in[0];
    const float* adj = (const float*)d_in[1];
    const float* Wq  = (const float*)d_in[2];
    const float* bq  = (const float*)d_in[3];
    const float* Wk  = (const float*)d_in[4];
    const float* bk  = (const float*)d_in[5];
    const float* Wv  = (const float*)d_in[6];
    const float* bv  = (const float*)d_in[7];
    float* out = (float*)d_out;

    // ws layout (ushort elems): xb[4M] | Wt[3M] | Qb[4M] | Kb[4M] | Vb[4M]  = ~39.8 MB
    ushort* xb = (ushort*)d_ws;
    ushort* Wt = xb + (size_t)Bn * Sn * Dn;           // 4,194,304
    ushort* Qb = Wt + (size_t)3 * Dn * Dn;            // +3,145,728
    ushort* Kb = Qb + (size_t)Bn * Hn * Sn * HDn;
    ushort* Vb = Kb + (size_t)Bn * Hn * Sn * HDn;

    convert_x<<<dim3((Bn * Sn * Dn) / (256 * 8)), 256, 0, stream>>>(x, xb);
    transpose_w<<<dim3(16, 16, 3), 256, 0, stream>>>(Wq, Wk, Wv, Wt);

    qkv_gemm<<<dim3(Dn / 128, (Bn * Sn) / 128, 3), 256, 0, stream>>>(
        xb, Wt, bq, bk, bv, Qb, Kb, Vb);

    attn<<<dim3(Sn / 64, Hn, Bn), 256, 0, stream>>>(Qb, Kb, Vb, adj, out);

    hipMemcpyAsync(out + (size_t)Bn * Sn * Dn, adj,
                   (size_t)Bn * Sn * Sn * sizeof(float),
                   hipMemcpyDeviceToDevice, stream);
}

// Round 3
// 224.884 us; speedup vs baseline: 3.1503x; 1.8590x over previous
//
#include <hip/hip_runtime.h>

constexpr int Bn  = 4;
constexpr int Sn  = 1024;
constexpr int Dn  = 1024;
constexpr int Hn  = 16;
constexpr int HDn = 64;

using short8  = __attribute__((ext_vector_type(8))) short;
using float4v = __attribute__((ext_vector_type(4))) float;

__device__ __forceinline__ ushort f2bf(float f) {
    union { float f; unsigned u; } v; v.f = f;
    unsigned r = v.u + 0x7fff + ((v.u >> 16) & 1);   // RNE
    return (ushort)(r >> 16);
}

// ---------------------------------------------------------------------------
// x (fp32, 4096x1024) -> xb (bf16 row-major). 8 floats/thread.
// ---------------------------------------------------------------------------
__global__ __launch_bounds__(256) void convert_x(const float* __restrict__ x,
                                                 ushort* __restrict__ xb)
{
    const size_t i = ((size_t)blockIdx.x * 256 + threadIdx.x) * 8;
    float4 a = *(const float4*)&x[i];
    float4 b = *(const float4*)&x[i + 4];
    ushort o[8] = {f2bf(a.x), f2bf(a.y), f2bf(a.z), f2bf(a.w),
                   f2bf(b.x), f2bf(b.y), f2bf(b.z), f2bf(b.w)};
    *(uint4*)&xb[i] = *(const uint4*)o;
}

// ---------------------------------------------------------------------------
// W[which] (K x N fp32 row-major) -> Wt (N x K bf16 row-major), 64x64 tiles.
// ---------------------------------------------------------------------------
__global__ __launch_bounds__(256) void transpose_w(
    const float* __restrict__ Wq, const float* __restrict__ Wk,
    const float* __restrict__ Wv, ushort* __restrict__ Wt)
{
    const int which = blockIdx.z;
    const float* __restrict__ W = (which == 0) ? Wq : (which == 1) ? Wk : Wv;
    ushort* __restrict__ O = Wt + (size_t)which * Dn * Dn;

    const int k0 = blockIdx.x * 64;
    const int n0 = blockIdx.y * 64;
    const int t  = threadIdx.x;

    __shared__ __align__(16) ushort T[64][72];

    const int kl = t >> 4;
    const int nl = (t & 15) * 4;
#pragma unroll
    for (int p = 0; p < 4; ++p) {
        float4 w = *(const float4*)&W[(size_t)(k0 + p * 16 + kl) * Dn + n0 + nl];
        T[nl + 0][p * 16 + kl] = f2bf(w.x);
        T[nl + 1][p * 16 + kl] = f2bf(w.y);
        T[nl + 2][p * 16 + kl] = f2bf(w.z);
        T[nl + 3][p * 16 + kl] = f2bf(w.w);
    }
    __syncthreads();
    const int nr = t >> 2;
    const int kc = (t & 3) * 16;
    uint4 u0 = *(const uint4*)&T[nr][kc];
    uint4 u1 = *(const uint4*)&T[nr][kc + 8];
    *(uint4*)&O[(size_t)(n0 + nr) * Dn + k0 + kc]     = u0;
    *(uint4*)&O[(size_t)(n0 + nr) * Dn + k0 + kc + 8] = u1;
}

// ---------------------------------------------------------------------------
// build_mask: swizzle adj into per-lane C-fragment order, bf16 0 / -1e7.
// rid = ((((b*8+qt)*16+kt)*4+w)*4+g)*16+n ; values ordered [i][r][jt].
// ---------------------------------------------------------------------------
__global__ __launch_bounds__(256) void build_mask(const float* __restrict__ adj,
                                                  ushort* __restrict__ Mw)
{
    const int rid = blockIdx.x * 256 + threadIdx.x;
    const int n  = rid & 15;
    const int g  = (rid >> 4) & 3;
    const int w  = (rid >> 6) & 3;
    const int kt = (rid >> 8) & 15;
    const int qt = (rid >> 12) & 7;
    const int b  = rid >> 15;
    const float* ap = adj + (size_t)b * Sn * Sn;

    ushort outv[32];
#pragma unroll
    for (int i = 0; i < 2; ++i)
#pragma unroll
        for (int r = 0; r < 4; ++r) {
            const int q = qt * 128 + w * 32 + i * 16 + g * 4 + r;
#pragma unroll
            for (int jt = 0; jt < 4; ++jt) {
                const int k = kt * 64 + jt * 16 + n;
                const float a = ap[(size_t)q * Sn + k];
                outv[(i * 4 + r) * 4 + jt] = (a < 0.5f) ? (ushort)0xCB19 : (ushort)0; // -1.0e7 bf16
            }
        }
    ushort* dst = Mw + (size_t)rid * 32;
#pragma unroll
    for (int c = 0; c < 4; ++c)
        *(uint4*)&dst[c * 8] = ((const uint4*)outv)[c];
}

// ---------------------------------------------------------------------------
// bf16 MFMA GEMM: Out = xb @ Wt^T + bias -> bf16 [B,H,S,HD]; Q pre-scaled 1/8.
// ---------------------------------------------------------------------------
__device__ __forceinline__ void gload16(const void* g, void* l) {
    __builtin_amdgcn_global_load_lds(
        (const __attribute__((address_space(1))) void*)g,
        (__attribute__((address_space(3))) void*)l, 16, 0, 0);
}

__global__ __launch_bounds__(256) void qkv_gemm(
    const ushort* __restrict__ xb, const ushort* __restrict__ Wt,
    const float* __restrict__ bq, const float* __restrict__ bk,
    const float* __restrict__ bv,
    ushort* __restrict__ Qb, ushort* __restrict__ Kb, ushort* __restrict__ Vb)
{
    const int which = blockIdx.z;
    const ushort* __restrict__ Bw   = Wt + (size_t)which * Dn * Dn;
    const float* __restrict__  bias = (which == 0) ? bq : (which == 1) ? bk : bv;
    ushort* __restrict__       Out  = (which == 0) ? Qb : (which == 1) ? Kb : Vb;
    const float scale = (which == 0) ? 0.125f : 1.0f;

    const int n0   = blockIdx.x * 128;
    const int m0   = blockIdx.y * 128;
    const int tid  = threadIdx.x;
    const int wave = tid >> 6;
    const int lane = tid & 63;
    const int wm   = wave >> 1;
    const int wn   = wave & 1;

    __shared__ __align__(16) ushort As[128 * 32];
    __shared__ __align__(16) ushort Bs[128 * 32];

    const int L0 = wave * 64 + lane;
    const int r0s = L0 >> 2, c0s = (L0 & 3) * 8;
    const int L1 = L0 + 256;
    const int r1s = L1 >> 2, c1s = (L1 & 3) * 8;

    const ushort* pA0 = &xb[(size_t)(m0 + r0s) * Dn + c0s];
    const ushort* pA1 = &xb[(size_t)(m0 + r1s) * Dn + c1s];
    const ushort* pB0 = &Bw[(size_t)(n0 + r0s) * Dn + c0s];
    const ushort* pB1 = &Bw[(size_t)(n0 + r1s) * Dn + c1s];

    char* ldsA0 = (char*)As + wave * 1024;
    char* ldsA1 = (char*)As + wave * 1024 + 4096;
    char* ldsB0 = (char*)Bs + wave * 1024;
    char* ldsB1 = (char*)Bs + wave * 1024 + 4096;

    const int mlane = lane & 15;
    const int kg    = (lane >> 4) * 8;

    float4v acc[4][4];
    const float4v z4 = {0.f, 0.f, 0.f, 0.f};
#pragma unroll
    for (int i = 0; i < 4; ++i)
#pragma unroll
        for (int j = 0; j < 4; ++j) acc[i][j] = z4;

    for (int k0 = 0; k0 < Dn; k0 += 32) {
        __syncthreads();
        gload16(pA0, ldsA0);
        gload16(pA1, ldsA1);
        gload16(pB0, ldsB0);
        gload16(pB1, ldsB1);
        pA0 += 32; pA1 += 32; pB0 += 32; pB1 += 32;
        __syncthreads();

        short8 af[4], bf[4];
#pragma unroll
        for (int i = 0; i < 4; ++i)
            af[i] = *(const short8*)&As[(wm * 64 + i * 16 + mlane) * 32 + kg];
#pragma unroll
        for (int j = 0; j < 4; ++j)
            bf[j] = *(const short8*)&Bs[(wn * 64 + j * 16 + mlane) * 32 + kg];
#pragma unroll
        for (int i = 0; i < 4; ++i)
#pragma unroll
            for (int j = 0; j < 4; ++j)
                acc[i][j] = __builtin_amdgcn_mfma_f32_16x16x32_bf16(af[i], bf[j], acc[i][j], 0, 0, 0);
    }

    const int rb  = (lane >> 4) * 4;
    const int col = lane & 15;
#pragma unroll
    for (int j = 0; j < 4; ++j) {
        const int n  = n0 + wn * 64 + j * 16 + col;
        const float bias_n = bias[n];
        const int h  = n >> 6;
        const int hd = n & 63;
#pragma unroll
        for (int i = 0; i < 4; ++i) {
#pragma unroll
            for (int r = 0; r < 4; ++r) {
                const int m = m0 + wm * 64 + i * 16 + rb + r;
                const int b = m >> 10;
                const int s = m & 1023;
                Out[(((size_t)(b * Hn + h)) * Sn + s) * HDn + hd] =
                    f2bf((acc[i][j][r] + bias_n) * scale);
            }
        }
    }
}

// ---------------------------------------------------------------------------
// MFMA flash attention. 1 block = 128 q-rows of one (b,h). 4 waves x 32 rows.
// All LDS panelized by 32-k, row stride 40 ushorts (16B-aligned, bank-spread).
// grid (8, 16, 4), block 256.
// ---------------------------------------------------------------------------
__global__ __launch_bounds__(256, 2) void attn_mfma(
    const ushort* __restrict__ Q, const ushort* __restrict__ K,
    const ushort* __restrict__ V, const ushort* __restrict__ Mw,
    float* __restrict__ out)
{
    const int qt = blockIdx.x;
    const int h  = blockIdx.y;
    const int b  = blockIdx.z;
    const int tid  = threadIdx.x;
    const int w    = tid >> 6;
    const int lane = tid & 63;
    const int ml   = lane & 15;
    const int g    = lane >> 4;
    const int kg   = g * 8;

    const size_t hb = ((size_t)(b * Hn + h)) * Sn * HDn;
    const ushort* Qg = Q + hb + (size_t)qt * 128 * HDn;

    __shared__ __align__(16) ushort Qs[2 * 128 * 40];   // [kp][row][40]
    __shared__ __align__(16) ushort Ks[2 * 64 * 40];    // [kp][key][40]  (k = dim)
    __shared__ __align__(16) ushort Vt[2 * 64 * 40];    // [kp][dim][40]  (k = key)
    __shared__ __align__(16) ushort Pb[2 * 128 * 40];   // [kp][row][40]  (k = key)

    // ---- stage Q (once) ----
#pragma unroll
    for (int p = 0; p < 4; ++p) {
        const int e = tid + 256 * p;
        const int row = e >> 3, kc = (e & 7) * 8;
        uint4 q4 = *(const uint4*)&Qg[row * 64 + kc];
        *(uint4*)&Qs[(kc >> 5) * 5120 + row * 40 + (kc & 31)] = q4;
    }

    const float4v z4 = {0.f, 0.f, 0.f, 0.f};
    float4v acc[2][4];
#pragma unroll
    for (int i = 0; i < 2; ++i)
#pragma unroll
        for (int jt = 0; jt < 4; ++jt) acc[i][jt] = z4;

    float m_i[2][4], l_i[2][4];
#pragma unroll
    for (int i = 0; i < 2; ++i)
#pragma unroll
        for (int r = 0; r < 4; ++r) { m_i[i][r] = -3.0e38f; l_i[i][r] = 0.f; }

    const int maskBase = ((((b * 8 + qt) * 16) * 4 + w) * 4 + g) * 16 + ml; // + kt*64*... via kt term below

    for (int kt = 0; kt < 16; ++kt) {
        const ushort* Kg = K + hb + (size_t)kt * 64 * HDn;
        const ushort* Vg = V + hb + (size_t)kt * 64 * HDn;

        __syncthreads();   // prior-iter Ks/Vt reads complete
        // stage K: [key][dim] -> Ks[kp][key][40]
#pragma unroll
        for (int p = 0; p < 2; ++p) {
            const int e = tid + 256 * p;
            const int row = e >> 3, kc = (e & 7) * 8;
            uint4 k4 = *(const uint4*)&Kg[row * 64 + kc];
            *(uint4*)&Ks[(kc >> 5) * 2560 + row * 40 + (kc & 31)] = k4;
        }
        // stage V transposed: Vt[key>>5][dim][key&31]
#pragma unroll
        for (int p = 0; p < 2; ++p) {
            const int db = w * 8 + 32 * p;
            uint4 v4 = *(const uint4*)&Vg[lane * 64 + db];
            const ushort* vs = (const ushort*)&v4;
            const int off = (lane >> 5) * 2560 + (lane & 31);
#pragma unroll
            for (int i2 = 0; i2 < 8; ++i2)
                Vt[off + (db + i2) * 40] = vs[i2];
        }

        // mask fragment: 4 coalesced uint4 loads
        const ushort* mp = Mw + ((size_t)(maskBase + (((b * 8 + qt) * 16 + kt) * 4) * 64 - (((b * 8 + qt) * 16) * 4) * 64)) * 32
                              + (size_t)0;
        // simpler: recompute rid directly
        const size_t rid = (size_t)(((((b * 8 + qt) * 16 + kt) * 4 + w) * 4 + g) * 16 + ml);
        const ushort* mpp = Mw + rid * 32;
        union { uint4 v[4]; ushort u[32]; } mk;
        mk.v[0] = *(const uint4*)&mpp[0];
        mk.v[1] = *(const uint4*)&mpp[8];
        mk.v[2] = *(const uint4*)&mpp[16];
        mk.v[3] = *(const uint4*)&mpp[24];

        float4v s_[2][4];
#pragma unroll
        for (int i = 0; i < 2; ++i)
#pragma unroll
            for (int jt = 0; jt < 4; ++jt)
#pragma unroll
                for (int r = 0; r < 4; ++r)
                    s_[i][jt][r] = __uint_as_float((unsigned)mk.u[(i * 4 + r) * 4 + jt] << 16);

        __syncthreads();   // staging visible

        // ---- QK^T (Q pre-scaled by 1/8) ----
#pragma unroll
        for (int ks = 0; ks < 2; ++ks) {
            short8 aq0 = *(const short8*)&Qs[ks * 5120 + (w * 32 + ml) * 40 + kg];
            short8 aq1 = *(const short8*)&Qs[ks * 5120 + (w * 32 + 16 + ml) * 40 + kg];
#pragma unroll
            for (int jt = 0; jt < 4; ++jt) {
                short8 bb = *(const short8*)&Ks[ks * 2560 + (jt * 16 + ml) * 40 + kg];
                s_[0][jt] = __builtin_amdgcn_mfma_f32_16x16x32_bf16(aq0, bb, s_[0][jt], 0, 0, 0);
                s_[1][jt] = __builtin_amdgcn_mfma_f32_16x16x32_bf16(aq1, bb, s_[1][jt], 0, 0, 0);
            }
        }

        // ---- online softmax (rows live in 16-lane groups: shfl_xor 1,2,4,8) ----
        float pp[2][4][4];
#pragma unroll
        for (int i = 0; i < 2; ++i) {
#pragma unroll
            for (int r = 0; r < 4; ++r) {
                float mt = fmaxf(fmaxf(s_[i][0][r], s_[i][1][r]), fmaxf(s_[i][2][r], s_[i][3][r]));
#pragma unroll
                for (int off = 1; off < 16; off <<= 1)
                    mt = fmaxf(mt, __shfl_xor(mt, off, 64));
                const float mnew  = fmaxf(m_i[i][r], mt);
                const float alpha = __expf(m_i[i][r] - mnew);
                float rs = 0.f;
#pragma unroll
                for (int jt = 0; jt < 4; ++jt) {
                    const float pv = __expf(s_[i][jt][r] - mnew);
                    pp[i][jt][r] = pv;
                    rs += pv;
                }
#pragma unroll
                for (int off = 1; off < 16; off <<= 1)
                    rs += __shfl_xor(rs, off, 64);
                l_i[i][r] = l_i[i][r] * alpha + rs;
                m_i[i][r] = mnew;
#pragma unroll
                for (int jt = 0; jt < 4; ++jt)
                    acc[i][jt][r] *= alpha;
            }
        }

        // ---- P -> LDS (bf16, wave-private rows: no barrier needed) ----
#pragma unroll
        for (int i = 0; i < 2; ++i)
#pragma unroll
            for (int jt = 0; jt < 4; ++jt) {
                const int base = (jt >> 1) * 5120 + (w * 32 + i * 16 + g * 4) * 40 + (jt & 1) * 16 + ml;
#pragma unroll
                for (int r = 0; r < 4; ++r)
                    Pb[base + r * 40] = f2bf(pp[i][jt][r]);
            }

        // ---- PV ----
#pragma unroll
        for (int ks = 0; ks < 2; ++ks) {
            short8 ap0 = *(const short8*)&Pb[ks * 5120 + (w * 32 + ml) * 40 + kg];
            short8 ap1 = *(const short8*)&Pb[ks * 5120 + (w * 32 + 16 + ml) * 40 + kg];
#pragma unroll
            for (int jt = 0; jt < 4; ++jt) {
                short8 bvv = *(const short8*)&Vt[ks * 2560 + (jt * 16 + ml) * 40 + kg];
                acc[0][jt] = __builtin_amdgcn_mfma_f32_16x16x32_bf16(ap0, bvv, acc[0][jt], 0, 0, 0);
                acc[1][jt] = __builtin_amdgcn_mfma_f32_16x16x32_bf16(ap1, bvv, acc[1][jt], 0, 0, 0);
            }
        }
    }

    // ---- epilogue: relu(acc / l) ----
#pragma unroll
    for (int i = 0; i < 2; ++i)
#pragma unroll
        for (int r = 0; r < 4; ++r) {
            const float inv = 1.0f / l_i[i][r];
            const int q = qt * 128 + w * 32 + i * 16 + g * 4 + r;
            float* op = &out[((size_t)b * Sn + q) * Dn + h * 64 + ml];
#pragma unroll
            for (int jt = 0; jt < 4; ++jt)
                op[jt * 16] = fmaxf(acc[i][jt][r] * inv, 0.0f);
        }
}

extern "C" void kernel_launch(void* const* d_in, const int* in_sizes, int n_in,
                              void* d_out, int out_size, void* d_ws, size_t ws_size,
                              hipStream_t stream)
{
    const float* x   = (const float*)d_in[0];
    const float* adj = (const float*)d_in[1];
    const float* Wq  = (const float*)d_in[2];
    const float* bq  = (const float*)d_in[3];
    const float* Wk  = (const float*)d_in[4];
    const float* bk  = (const float*)d_in[5];
    const float* Wv  = (const float*)d_in[6];
    const float* bv  = (const float*)d_in[7];
    float* out = (float*)d_out;

    // ws (ushort): xb[4.19M] | Wt[3.15M] | Qb | Kb | Vb | Mw[4.19M]  = 48.2 MB
    ushort* xb = (ushort*)d_ws;
    ushort* Wt = xb + (size_t)Bn * Sn * Dn;
    ushort* Qb = Wt + (size_t)3 * Dn * Dn;
    ushort* Kb = Qb + (size_t)Bn * Hn * Sn * HDn;
    ushort* Vb = Kb + (size_t)Bn * Hn * Sn * HDn;
    ushort* Mw = Vb + (size_t)Bn * Hn * Sn * HDn;

    convert_x<<<dim3((Bn * Sn * Dn) / (256 * 8)), 256, 0, stream>>>(x, xb);
    transpose_w<<<dim3(16, 16, 3), 256, 0, stream>>>(Wq, Wk, Wv, Wt);
    build_mask<<<dim3((Bn * Sn * Sn / 32) / 256), 256, 0, stream>>>(adj, Mw);

    qkv_gemm<<<dim3(Dn / 128, (Bn * Sn) / 128, 3), 256, 0, stream>>>(
        xb, Wt, bq, bk, bv, Qb, Kb, Vb);

    attn_mfma<<<dim3(Sn / 128, Hn, Bn), 256, 0, stream>>>(Qb, Kb, Vb, Mw, out);

    hipMemcpyAsync(out + (size_t)Bn * Sn * Dn, adj,
                   (size_t)Bn * Sn * Sn * sizeof(float),
                   hipMemcpyDeviceToDevice, stream);
}

// Round 4
// 206.531 us; speedup vs baseline: 3.4302x; 1.0889x over previous
//
#include <hip/hip_runtime.h>

constexpr int Bn  = 4;
constexpr int Sn  = 1024;
constexpr int Dn  = 1024;
constexpr int Hn  = 16;
constexpr int HDn = 64;

using short8  = __attribute__((ext_vector_type(8))) short;
using float4v = __attribute__((ext_vector_type(4))) float;

__device__ __forceinline__ ushort f2bf(float f) {
    union { float f; unsigned u; } v; v.f = f;
    unsigned r = v.u + 0x7fff + ((v.u >> 16) & 1);   // RNE
    return (ushort)(r >> 16);
}

__device__ __forceinline__ void gload16(const void* g, void* l) {
    __builtin_amdgcn_global_load_lds(
        (const __attribute__((address_space(1))) void*)g,
        (__attribute__((address_space(3))) void*)l, 16, 0, 0);
}

// ---------------------------------------------------------------------------
// x (fp32) -> xb (bf16 row-major)
// ---------------------------------------------------------------------------
__global__ __launch_bounds__(256) void convert_x(const float* __restrict__ x,
                                                 ushort* __restrict__ xb)
{
    const size_t i = ((size_t)blockIdx.x * 256 + threadIdx.x) * 8;
    float4 a = *(const float4*)&x[i];
    float4 b = *(const float4*)&x[i + 4];
    ushort o[8] = {f2bf(a.x), f2bf(a.y), f2bf(a.z), f2bf(a.w),
                   f2bf(b.x), f2bf(b.y), f2bf(b.z), f2bf(b.w)};
    *(uint4*)&xb[i] = *(const uint4*)o;
}

// ---------------------------------------------------------------------------
// W (K x N fp32) -> Wt (N x K bf16)
// ---------------------------------------------------------------------------
__global__ __launch_bounds__(256) void transpose_w(
    const float* __restrict__ Wq, const float* __restrict__ Wk,
    const float* __restrict__ Wv, ushort* __restrict__ Wt)
{
    const int which = blockIdx.z;
    const float* __restrict__ W = (which == 0) ? Wq : (which == 1) ? Wk : Wv;
    ushort* __restrict__ O = Wt + (size_t)which * Dn * Dn;

    const int k0 = blockIdx.x * 64;
    const int n0 = blockIdx.y * 64;
    const int t  = threadIdx.x;

    __shared__ __align__(16) ushort T[64][72];

    const int kl = t >> 4;
    const int nl = (t & 15) * 4;
#pragma unroll
    for (int p = 0; p < 4; ++p) {
        float4 w = *(const float4*)&W[(size_t)(k0 + p * 16 + kl) * Dn + n0 + nl];
        T[nl + 0][p * 16 + kl] = f2bf(w.x);
        T[nl + 1][p * 16 + kl] = f2bf(w.y);
        T[nl + 2][p * 16 + kl] = f2bf(w.z);
        T[nl + 3][p * 16 + kl] = f2bf(w.w);
    }
    __syncthreads();
    const int nr = t >> 2;
    const int kc = (t & 3) * 16;
    uint4 u0 = *(const uint4*)&T[nr][kc];
    uint4 u1 = *(const uint4*)&T[nr][kc + 8];
    *(uint4*)&O[(size_t)(n0 + nr) * Dn + k0 + kc]     = u0;
    *(uint4*)&O[(size_t)(n0 + nr) * Dn + k0 + kc + 8] = u1;
}

// ---------------------------------------------------------------------------
// build_mask: adj tile [128 q][64 k] -> per-lane S^T C-fragment order (bf16).
// Coalesced loads via LDS transpose. grid (8 qt, 16 kt, 4 b), block 256.
// Lane element order: u[(mt*2+jt)*4+r] for key=mt*16+g*4+r, qrow=w*32+jt*16+ml.
// ---------------------------------------------------------------------------
__global__ __launch_bounds__(256) void build_mask(const float* __restrict__ adj,
                                                  ushort* __restrict__ Mw)
{
    const int qt = blockIdx.x, kt = blockIdx.y, b = blockIdx.z;
    const int tid = threadIdx.x;

    __shared__ ushort msk[128][68];   // stride 68: b64-aligned, bank-spread

    const float* ap = adj + ((size_t)b * Sn + qt * 128) * Sn + kt * 64;
#pragma unroll
    for (int c = 0; c < 8; ++c) {
        const int e = tid + 256 * c, row = e >> 4, c4 = (e & 15) * 4;
        float4 a = *(const float4*)&ap[(size_t)row * Sn + c4];
        ushort m[4] = {(ushort)(a.x < 0.5f ? 0xCB19 : 0), (ushort)(a.y < 0.5f ? 0xCB19 : 0),
                       (ushort)(a.z < 0.5f ? 0xCB19 : 0), (ushort)(a.w < 0.5f ? 0xCB19 : 0)};
        *(uint2*)&msk[row][c4] = *(const uint2*)m;
    }
    __syncthreads();

    const int w = tid >> 6, g = (tid >> 4) & 3, ml = tid & 15;
    ushort u[32];
#pragma unroll
    for (int mt = 0; mt < 4; ++mt)
#pragma unroll
        for (int j = 0; j < 2; ++j)
#pragma unroll
            for (int r = 0; r < 4; ++r)
                u[(mt * 2 + j) * 4 + r] = msk[w * 32 + j * 16 + ml][mt * 16 + g * 4 + r];

    ushort* dst = Mw + (((((size_t)((b * 8 + qt) * 16 + kt)) * 4 + w) * 4 + g) * 16 + ml) * 32;
#pragma unroll
    for (int c = 0; c < 4; ++c)
        *(uint4*)&dst[c * 8] = ((const uint4*)u)[c];
}

// ---------------------------------------------------------------------------
// bf16 MFMA GEMM: Q pre-scaled 1/8, Q/K -> [B,H,S,HD], V -> [B,H,HD,S] (transposed)
// ---------------------------------------------------------------------------
__global__ __launch_bounds__(256) void qkv_gemm(
    const ushort* __restrict__ xb, const ushort* __restrict__ Wt,
    const float* __restrict__ bq, const float* __restrict__ bk,
    const float* __restrict__ bv,
    ushort* __restrict__ Qb, ushort* __restrict__ Kb, ushort* __restrict__ Vb)
{
    const int which = blockIdx.z;
    const ushort* __restrict__ Bw   = Wt + (size_t)which * Dn * Dn;
    const float* __restrict__  bias = (which == 0) ? bq : (which == 1) ? bk : bv;
    ushort* __restrict__       Out  = (which == 0) ? Qb : (which == 1) ? Kb : Vb;
    const float scale = (which == 0) ? 0.125f : 1.0f;

    const int n0   = blockIdx.x * 128;
    const int m0   = blockIdx.y * 128;
    const int tid  = threadIdx.x;
    const int wave = tid >> 6;
    const int lane = tid & 63;
    const int wm   = wave >> 1;
    const int wn   = wave & 1;

    __shared__ __align__(16) ushort As[128 * 32];
    __shared__ __align__(16) ushort Bs[128 * 32];

    const int L0 = wave * 64 + lane;
    const int r0s = L0 >> 2, c0s = (L0 & 3) * 8;
    const int L1 = L0 + 256;
    const int r1s = L1 >> 2, c1s = (L1 & 3) * 8;

    const ushort* pA0 = &xb[(size_t)(m0 + r0s) * Dn + c0s];
    const ushort* pA1 = &xb[(size_t)(m0 + r1s) * Dn + c1s];
    const ushort* pB0 = &Bw[(size_t)(n0 + r0s) * Dn + c0s];
    const ushort* pB1 = &Bw[(size_t)(n0 + r1s) * Dn + c1s];

    char* ldsA0 = (char*)As + wave * 1024;
    char* ldsA1 = (char*)As + wave * 1024 + 4096;
    char* ldsB0 = (char*)Bs + wave * 1024;
    char* ldsB1 = (char*)Bs + wave * 1024 + 4096;

    const int mlane = lane & 15;
    const int kg    = (lane >> 4) * 8;

    float4v acc[4][4];
    const float4v z4 = {0.f, 0.f, 0.f, 0.f};
#pragma unroll
    for (int i = 0; i < 4; ++i)
#pragma unroll
        for (int j = 0; j < 4; ++j) acc[i][j] = z4;

    for (int k0 = 0; k0 < Dn; k0 += 32) {
        __syncthreads();
        gload16(pA0, ldsA0);
        gload16(pA1, ldsA1);
        gload16(pB0, ldsB0);
        gload16(pB1, ldsB1);
        pA0 += 32; pA1 += 32; pB0 += 32; pB1 += 32;
        __syncthreads();

        short8 af[4], bf[4];
#pragma unroll
        for (int i = 0; i < 4; ++i)
            af[i] = *(const short8*)&As[(wm * 64 + i * 16 + mlane) * 32 + kg];
#pragma unroll
        for (int j = 0; j < 4; ++j)
            bf[j] = *(const short8*)&Bs[(wn * 64 + j * 16 + mlane) * 32 + kg];
#pragma unroll
        for (int i = 0; i < 4; ++i)
#pragma unroll
            for (int j = 0; j < 4; ++j)
                acc[i][j] = __builtin_amdgcn_mfma_f32_16x16x32_bf16(af[i], bf[j], acc[i][j], 0, 0, 0);
    }

    const int rb  = (lane >> 4) * 4;
    const int col = lane & 15;
#pragma unroll
    for (int j = 0; j < 4; ++j) {
        const int n  = n0 + wn * 64 + j * 16 + col;
        const float bias_n = bias[n];
        const int h  = n >> 6;
        const int hd = n & 63;
#pragma unroll
        for (int i = 0; i < 4; ++i) {
#pragma unroll
            for (int r = 0; r < 4; ++r) {
                const int m = m0 + wm * 64 + i * 16 + rb + r;
                const int b = m >> 10;
                const int s = m & 1023;
                size_t addr;
                if (which == 2)
                    addr = (((size_t)(b * Hn + h)) * HDn + hd) * Sn + s;   // V transposed
                else
                    addr = (((size_t)(b * Hn + h)) * Sn + s) * HDn + hd;
                Out[addr] = f2bf((acc[i][j][r] + bias_n) * scale);
            }
        }
    }
}

// ---------------------------------------------------------------------------
// MFMA flash attention, transposed formulation, no-max softmax.
// S^T = K·Q^T (mask in C-init); p = exp(s) (masked -> exact 0);
// O^T = V^T·P^T. Deferred row-sum: local Σp, one shfl reduction at end.
// grid (8 qt, 16 h, 4 b), block 256 (4 waves x 32 q-rows).
// ---------------------------------------------------------------------------
__global__ __launch_bounds__(256, 2) void attn_mfma(
    const ushort* __restrict__ Q, const ushort* __restrict__ K,
    const ushort* __restrict__ Vt, const ushort* __restrict__ Mw,
    float* __restrict__ out)
{
    const int qt = blockIdx.x, h = blockIdx.y, b = blockIdx.z;
    const int tid = threadIdx.x;
    const int w = tid >> 6, lane = tid & 63;
    const int ml = lane & 15, g = lane >> 4, kg = g * 8;

    const size_t hb = ((size_t)(b * Hn + h)) * Sn * HDn;
    const ushort* Kg = K + hb;            // [s][hd]
    const ushort* Vg = Vt + hb;           // [hd][s]

    __shared__ __align__(16) ushort Ks[2 * 64 * 32];   // [kp dim-panel][key][32]
    __shared__ __align__(16) ushort Vs[2 * 64 * 32];   // [kp key-panel][dim][32]
    __shared__ __align__(16) ushort Pb[2 * 128 * 40];  // [kp key-panel][qrow][40]

    // Q fragments: direct global -> registers, reused for all kt.
    short8 bq[2][2];
#pragma unroll
    for (int kp = 0; kp < 2; ++kp)
#pragma unroll
        for (int j = 0; j < 2; ++j)
            bq[kp][j] = *(const short8*)&Q[hb + (size_t)(qt * 128 + w * 32 + j * 16 + ml) * HDn
                                           + kp * 32 + kg];

    const float4v z4 = {0.f, 0.f, 0.f, 0.f};
    float4v acc[4][2];
#pragma unroll
    for (int mt = 0; mt < 4; ++mt)
#pragma unroll
        for (int j = 0; j < 2; ++j) acc[mt][j] = z4;
    float ls[2] = {0.f, 0.f};

    for (int kt = 0; kt < 16; ++kt) {
        __syncthreads();   // prior-iter Ks/Vs reads complete
        // stage K tile [64 keys][64 dims] and V^T tile [64 dims][64 keys]
#pragma unroll
        for (int p = 0; p < 2; ++p) {
            const int e = tid + 256 * p, row = e >> 3, cc = e & 7;
            uint4 k4 = *(const uint4*)&Kg[(size_t)(kt * 64 + row) * HDn + cc * 8];
            *(uint4*)&Ks[(cc >> 2) * 2048 + row * 32 + (cc & 3) * 8] = k4;
            uint4 v4 = *(const uint4*)&Vg[(size_t)row * Sn + kt * 64 + cc * 8];
            *(uint4*)&Vs[(cc >> 2) * 2048 + row * 32 + (cc & 3) * 8] = v4;
        }

        // mask fragment (C-init for S^T)
        const ushort* mp = Mw + (((((size_t)((b * 8 + qt) * 16 + kt)) * 4 + w) * 4 + g) * 16 + ml) * 32;
        union { uint4 v[4]; ushort u[32]; } mk;
        mk.v[0] = *(const uint4*)&mp[0];
        mk.v[1] = *(const uint4*)&mp[8];
        mk.v[2] = *(const uint4*)&mp[16];
        mk.v[3] = *(const uint4*)&mp[24];

        float4v s_[4][2];
#pragma unroll
        for (int mt = 0; mt < 4; ++mt)
#pragma unroll
            for (int j = 0; j < 2; ++j)
#pragma unroll
                for (int r = 0; r < 4; ++r)
                    s_[mt][j][r] = __uint_as_float((unsigned)mk.u[(mt * 2 + j) * 4 + r] << 16);

        __syncthreads();   // staging visible

        // ---- S^T = K·Q^T : A = K rows (m=key), B = Q rows (n=qrow) ----
#pragma unroll
        for (int kp = 0; kp < 2; ++kp)
#pragma unroll
            for (int mt = 0; mt < 4; ++mt) {
                short8 ak = *(const short8*)&Ks[kp * 2048 + (mt * 16 + ml) * 32 + kg];
                s_[mt][0] = __builtin_amdgcn_mfma_f32_16x16x32_bf16(ak, bq[kp][0], s_[mt][0], 0, 0, 0);
                s_[mt][1] = __builtin_amdgcn_mfma_f32_16x16x32_bf16(ak, bq[kp][1], s_[mt][1], 0, 0, 0);
            }

        // ---- p = exp(s); local row-sum; packed bf16 -> Pb[qrow][key] ----
#pragma unroll
        for (int mt = 0; mt < 4; ++mt)
#pragma unroll
            for (int j = 0; j < 2; ++j) {
                const float p0 = __expf(s_[mt][j][0]);
                const float p1 = __expf(s_[mt][j][1]);
                const float p2 = __expf(s_[mt][j][2]);
                const float p3 = __expf(s_[mt][j][3]);
                ls[j] += (p0 + p1) + (p2 + p3);
                uint2 d;
                d.x = (unsigned)f2bf(p0) | ((unsigned)f2bf(p1) << 16);
                d.y = (unsigned)f2bf(p2) | ((unsigned)f2bf(p3) << 16);
                *(uint2*)&Pb[(mt >> 1) * 5120 + (w * 32 + j * 16 + ml) * 40 + (mt & 1) * 16 + g * 4] = d;
            }
        // Pb rows are wave-private: no barrier needed (lgkmcnt ordering suffices)

        // ---- O^T += V^T·P^T : A = V^T rows (m=dim), B = P rows (n=qrow) ----
#pragma unroll
        for (int kp = 0; kp < 2; ++kp) {
            short8 bp0 = *(const short8*)&Pb[kp * 5120 + (w * 32 + ml) * 40 + kg];
            short8 bp1 = *(const short8*)&Pb[kp * 5120 + (w * 32 + 16 + ml) * 40 + kg];
#pragma unroll
            for (int mt = 0; mt < 4; ++mt) {
                short8 av = *(const short8*)&Vs[kp * 2048 + (mt * 16 + ml) * 32 + kg];
                acc[mt][0] = __builtin_amdgcn_mfma_f32_16x16x32_bf16(av, bp0, acc[mt][0], 0, 0, 0);
                acc[mt][1] = __builtin_amdgcn_mfma_f32_16x16x32_bf16(av, bp1, acc[mt][1], 0, 0, 0);
            }
        }
    }

    // ---- epilogue: row-sum reduce over g, relu(acc/l), float4 stores ----
#pragma unroll
    for (int j = 0; j < 2; ++j) {
        float l = ls[j];
        l += __shfl_xor(l, 16, 64);
        l += __shfl_xor(l, 32, 64);
        const float inv = 1.0f / l;
        const int q = qt * 128 + w * 32 + j * 16 + ml;
#pragma unroll
        for (int mt = 0; mt < 4; ++mt) {
            float4 o;
            o.x = fmaxf(acc[mt][j][0] * inv, 0.0f);
            o.y = fmaxf(acc[mt][j][1] * inv, 0.0f);
            o.z = fmaxf(acc[mt][j][2] * inv, 0.0f);
            o.w = fmaxf(acc[mt][j][3] * inv, 0.0f);
            *(float4*)&out[((size_t)b * Sn + q) * Dn + h * 64 + mt * 16 + g * 4] = o;
        }
    }
}

extern "C" void kernel_launch(void* const* d_in, const int* in_sizes, int n_in,
                              void* d_out, int out_size, void* d_ws, size_t ws_size,
                              hipStream_t stream)
{
    const float* x   = (const float*)d_in[0];
    const float* adj = (const float*)d_in[1];
    const float* Wq  = (const float*)d_in[2];
    const float* bq  = (const float*)d_in[3];
    const float* Wk  = (const float*)d_in[4];
    const float* bk  = (const float*)d_in[5];
    const float* Wv  = (const float*)d_in[6];
    const float* bv  = (const float*)d_in[7];
    float* out = (float*)d_out;

    // ws (ushort): xb | Wt | Qb | Kb | Vb | Mw  = ~48.2 MB
    ushort* xb = (ushort*)d_ws;
    ushort* Wt = xb + (size_t)Bn * Sn * Dn;
    ushort* Qb = Wt + (size_t)3 * Dn * Dn;
    ushort* Kb = Qb + (size_t)Bn * Hn * Sn * HDn;
    ushort* Vb = Kb + (size_t)Bn * Hn * Sn * HDn;
    ushort* Mw = Vb + (size_t)Bn * Hn * Sn * HDn;

    convert_x<<<dim3((Bn * Sn * Dn) / (256 * 8)), 256, 0, stream>>>(x, xb);
    transpose_w<<<dim3(16, 16, 3), 256, 0, stream>>>(Wq, Wk, Wv, Wt);
    build_mask<<<dim3(8, 16, 4), 256, 0, stream>>>(adj, Mw);

    qkv_gemm<<<dim3(Dn / 128, (Bn * Sn) / 128, 3), 256, 0, stream>>>(
        xb, Wt, bq, bk, bv, Qb, Kb, Vb);

    attn_mfma<<<dim3(Sn / 128, Hn, Bn), 256, 0, stream>>>(Qb, Kb, Vb, Mw, out);

    hipMemcpyAsync(out + (size_t)Bn * Sn * Dn, adj,
                   (size_t)Bn * Sn * Sn * sizeof(float),
                   hipMemcpyDeviceToDevice, stream);
}

// Round 6
// 192.484 us; speedup vs baseline: 3.6806x; 1.0730x over previous
//
#include <hip/hip_runtime.h>

constexpr int Bn  = 4;
constexpr int Sn  = 1024;
constexpr int Dn  = 1024;
constexpr int Hn  = 16;
constexpr int HDn = 64;

using short8   = __attribute__((ext_vector_type(8))) short;
using float4v  = __attribute__((ext_vector_type(4))) float;
using float16v = __attribute__((ext_vector_type(16))) float;

__device__ __forceinline__ ushort f2bf(float f) {
    union { float f; unsigned u; } v; v.f = f;
    unsigned r = v.u + 0x7fff + ((v.u >> 16) & 1);   // RNE
    return (ushort)(r >> 16);
}

__device__ __forceinline__ void gload16(const void* g, void* l) {
    __builtin_amdgcn_global_load_lds(
        (const __attribute__((address_space(1))) void*)g,
        (__attribute__((address_space(3))) void*)l, 16, 0, 0);
}

// ---------------------------------------------------------------------------
// x (fp32) -> xb (bf16 row-major)
// ---------------------------------------------------------------------------
__global__ __launch_bounds__(256) void convert_x(const float* __restrict__ x,
                                                 ushort* __restrict__ xb)
{
    const size_t i = ((size_t)blockIdx.x * 256 + threadIdx.x) * 8;
    float4 a = *(const float4*)&x[i];
    float4 b = *(const float4*)&x[i + 4];
    ushort o[8] = {f2bf(a.x), f2bf(a.y), f2bf(a.z), f2bf(a.w),
                   f2bf(b.x), f2bf(b.y), f2bf(b.z), f2bf(b.w)};
    *(uint4*)&xb[i] = *(const uint4*)o;
}

// ---------------------------------------------------------------------------
// W (K x N fp32) -> Wt (N x K bf16)
// ---------------------------------------------------------------------------
__global__ __launch_bounds__(256) void transpose_w(
    const float* __restrict__ Wq, const float* __restrict__ Wk,
    const float* __restrict__ Wv, ushort* __restrict__ Wt)
{
    const int which = blockIdx.z;
    const float* __restrict__ W = (which == 0) ? Wq : (which == 1) ? Wk : Wv;
    ushort* __restrict__ O = Wt + (size_t)which * Dn * Dn;

    const int k0 = blockIdx.x * 64;
    const int n0 = blockIdx.y * 64;
    const int t  = threadIdx.x;

    __shared__ __align__(16) ushort T[64][72];

    const int kl = t >> 4;
    const int nl = (t & 15) * 4;
#pragma unroll
    for (int p = 0; p < 4; ++p) {
        float4 w = *(const float4*)&W[(size_t)(k0 + p * 16 + kl) * Dn + n0 + nl];
        T[nl + 0][p * 16 + kl] = f2bf(w.x);
        T[nl + 1][p * 16 + kl] = f2bf(w.y);
        T[nl + 2][p * 16 + kl] = f2bf(w.z);
        T[nl + 3][p * 16 + kl] = f2bf(w.w);
    }
    __syncthreads();
    const int nr = t >> 2;
    const int kc = (t & 3) * 16;
    uint4 u0 = *(const uint4*)&T[nr][kc];
    uint4 u1 = *(const uint4*)&T[nr][kc + 8];
    *(uint4*)&O[(size_t)(n0 + nr) * Dn + k0 + kc]     = u0;
    *(uint4*)&O[(size_t)(n0 + nr) * Dn + k0 + kc + 8] = u1;
}

// ---------------------------------------------------------------------------
// build_mask: 1 bit per (q,key), laid out in 32x32 MFMA C-fragment order.
// rid = (((b*4+qt)*16+kt)*4+w)*64+lane; uint2 = 64 bits:
//   word mt, bit jt*16 + reg; q = qt*256+w*64+jt*32+(lane&31);
//   key = kt*64 + mt*32 + (reg&3) + 8*(reg>>2) + 4*(lane>>5).
// ---------------------------------------------------------------------------
__global__ __launch_bounds__(256) void build_mask(const float* __restrict__ adj,
                                                  uint2* __restrict__ Mb)
{
    const int rid  = blockIdx.x * 256 + threadIdx.x;
    const int lane = rid & 63;
    const int w    = (rid >> 6) & 3;
    const int kt   = (rid >> 8) & 15;
    const int qt   = (rid >> 12) & 3;
    const int b    = rid >> 14;
    const int col  = lane & 31, hi = lane >> 5;

    unsigned bits[2] = {0u, 0u};
#pragma unroll
    for (int mt = 0; mt < 2; ++mt)
#pragma unroll
        for (int jt = 0; jt < 2; ++jt) {
            const int q = qt * 256 + w * 64 + jt * 32 + col;
            const float* row = adj + ((size_t)b * Sn + q) * Sn;
#pragma unroll
            for (int rg = 0; rg < 4; ++rg) {
                float4 a = *(const float4*)&row[kt * 64 + mt * 32 + rg * 8 + hi * 4];
                unsigned bb = (a.x >= 0.5f ? 1u : 0u) | (a.y >= 0.5f ? 2u : 0u) |
                              (a.z >= 0.5f ? 4u : 0u) | (a.w >= 0.5f ? 8u : 0u);
                bits[mt] |= bb << (jt * 16 + rg * 4);
            }
        }
    Mb[rid] = make_uint2(bits[0], bits[1]);
}

// ---------------------------------------------------------------------------
// bf16 MFMA GEMM: Q pre-scaled 1/8, Q/K -> [B,H,S,HD], V -> [B,H,HD,S]
// ---------------------------------------------------------------------------
__global__ __launch_bounds__(256) void qkv_gemm(
    const ushort* __restrict__ xb, const ushort* __restrict__ Wt,
    const float* __restrict__ bq, const float* __restrict__ bk,
    const float* __restrict__ bv,
    ushort* __restrict__ Qb, ushort* __restrict__ Kb, ushort* __restrict__ Vb)
{
    const int which = blockIdx.z;
    const ushort* __restrict__ Bw   = Wt + (size_t)which * Dn * Dn;
    const float* __restrict__  bias = (which == 0) ? bq : (which == 1) ? bk : bv;
    ushort* __restrict__       Out  = (which == 0) ? Qb : (which == 1) ? Kb : Vb;
    const float scale = (which == 0) ? 0.125f : 1.0f;

    const int n0   = blockIdx.x * 128;
    const int m0   = blockIdx.y * 128;
    const int tid  = threadIdx.x;
    const int wave = tid >> 6;
    const int lane = tid & 63;
    const int wm   = wave >> 1;
    const int wn   = wave & 1;

    __shared__ __align__(16) ushort As[128 * 32];
    __shared__ __align__(16) ushort Bs[128 * 32];

    const int L0 = wave * 64 + lane;
    const int r0s = L0 >> 2, c0s = (L0 & 3) * 8;
    const int L1 = L0 + 256;
    const int r1s = L1 >> 2, c1s = (L1 & 3) * 8;

    const ushort* pA0 = &xb[(size_t)(m0 + r0s) * Dn + c0s];
    const ushort* pA1 = &xb[(size_t)(m0 + r1s) * Dn + c1s];
    const ushort* pB0 = &Bw[(size_t)(n0 + r0s) * Dn + c0s];
    const ushort* pB1 = &Bw[(size_t)(n0 + r1s) * Dn + c1s];

    char* ldsA0 = (char*)As + wave * 1024;
    char* ldsA1 = (char*)As + wave * 1024 + 4096;
    char* ldsB0 = (char*)Bs + wave * 1024;
    char* ldsB1 = (char*)Bs + wave * 1024 + 4096;

    const int mlane = lane & 15;
    const int kg    = (lane >> 4) * 8;

    float4v acc[4][4];
    const float4v z4 = {0.f, 0.f, 0.f, 0.f};
#pragma unroll
    for (int i = 0; i < 4; ++i)
#pragma unroll
        for (int j = 0; j < 4; ++j) acc[i][j] = z4;

    for (int k0 = 0; k0 < Dn; k0 += 32) {
        __syncthreads();
        gload16(pA0, ldsA0);
        gload16(pA1, ldsA1);
        gload16(pB0, ldsB0);
        gload16(pB1, ldsB1);
        pA0 += 32; pA1 += 32; pB0 += 32; pB1 += 32;
        __syncthreads();

        short8 af[4], bf[4];
#pragma unroll
        for (int i = 0; i < 4; ++i)
            af[i] = *(const short8*)&As[(wm * 64 + i * 16 + mlane) * 32 + kg];
#pragma unroll
        for (int j = 0; j < 4; ++j)
            bf[j] = *(const short8*)&Bs[(wn * 64 + j * 16 + mlane) * 32 + kg];
#pragma unroll
        for (int i = 0; i < 4; ++i)
#pragma unroll
            for (int j = 0; j < 4; ++j)
                acc[i][j] = __builtin_amdgcn_mfma_f32_16x16x32_bf16(af[i], bf[j], acc[i][j], 0, 0, 0);
    }

    const int rb  = (lane >> 4) * 4;
    const int col = lane & 15;
#pragma unroll
    for (int j = 0; j < 4; ++j) {
        const int n  = n0 + wn * 64 + j * 16 + col;
        const float bias_n = bias[n];
        const int h  = n >> 6;
        const int hd = n & 63;
#pragma unroll
        for (int i = 0; i < 4; ++i) {
#pragma unroll
            for (int r = 0; r < 4; ++r) {
                const int m = m0 + wm * 64 + i * 16 + rb + r;
                const int b = m >> 10;
                const int s = m & 1023;
                size_t addr;
                if (which == 2)
                    addr = (((size_t)(b * Hn + h)) * HDn + hd) * Sn + s;   // V transposed
                else
                    addr = (((size_t)(b * Hn + h)) * Sn + s) * HDn + hd;
                Out[addr] = f2bf((acc[i][j][r] + bias_n) * scale);
            }
        }
    }
}

// ---------------------------------------------------------------------------
// MFMA flash attention, 32x32x16, P stays in registers (shfl C->B transform),
// bitmask, no-max softmax with deferred row sum.
// Block = 256 q-rows of one (b,h): 4 waves x 64 q. grid (4,16,4) = 1 block/CU.
// LDS: K-tile + V^T-tile only, row stride 72 ushorts (144 B: 16B-aligned,
// 4-way quad sharing = 512B/128B-per-cycle floor), double-buffered. 36 KB.
// ---------------------------------------------------------------------------
__global__ __launch_bounds__(256, 1) void attn_mfma(
    const ushort* __restrict__ Q, const ushort* __restrict__ K,
    const ushort* __restrict__ Vt, const uint2* __restrict__ Mb,
    float* __restrict__ out)
{
    const int qt = blockIdx.x, h = blockIdx.y, b = blockIdx.z;
    const int tid  = threadIdx.x;
    const int w    = tid >> 6, lane = tid & 63;
    const int col  = lane & 31, hi = lane >> 5;

    const size_t hb = ((size_t)(b * Hn + h)) * Sn * HDn;
    const ushort* Kg = K + hb;          // [key][dim]
    const ushort* Vg = Vt + hb;         // [dim][key]

    __shared__ __align__(16) ushort Ks[2][64 * 72];
    __shared__ __align__(16) ushort Vs[2][64 * 72];

    // Q B-frags (registers, all 16 kt): B[k=dim][n=q], lane n=col, k=kp*16+hi*8+i
    short8 qf[2][4];
#pragma unroll
    for (int jt = 0; jt < 2; ++jt)
#pragma unroll
        for (int kp = 0; kp < 4; ++kp)
            qf[jt][kp] = *(const short8*)&Q[hb +
                (size_t)(qt * 256 + w * 64 + jt * 32 + col) * HDn + kp * 16 + hi * 8];

    float16v o_[2][2];   // [dim-tile][q-tile]
#pragma unroll
    for (int dt = 0; dt < 2; ++dt)
#pragma unroll
        for (int jt = 0; jt < 2; ++jt)
#pragma unroll
            for (int r = 0; r < 16; ++r) o_[dt][jt][r] = 0.f;
    float ls[2] = {0.f, 0.f};

    // staging: chunk c -> row c>>3, 8-elem chunk (c&7); lds = row*72 + (c&7)*8
    const int c0 = tid, c1 = tid + 256;
    const int la0 = (c0 >> 3) * 72 + (c0 & 7) * 8;
    const int la1 = (c1 >> 3) * 72 + (c1 & 7) * 8;

    uint4 k0 = *(const uint4*)&Kg[(size_t)(c0 >> 3) * HDn + (c0 & 7) * 8];
    uint4 k1 = *(const uint4*)&Kg[(size_t)(c1 >> 3) * HDn + (c1 & 7) * 8];
    uint4 v0 = *(const uint4*)&Vg[(size_t)(c0 >> 3) * Sn + (c0 & 7) * 8];
    uint4 v1 = *(const uint4*)&Vg[(size_t)(c1 >> 3) * Sn + (c1 & 7) * 8];
    *(uint4*)&Ks[0][la0] = k0;  *(uint4*)&Ks[0][la1] = k1;
    *(uint4*)&Vs[0][la0] = v0;  *(uint4*)&Vs[0][la1] = v1;
    __syncthreads();

    const uint2* mbase = Mb + ((size_t)(((b * 4 + qt) * 16) * 4 + w)) * 64 + lane;

    for (int kt = 0; kt < 16; ++kt) {
        const int cur = kt & 1;
        // prefetch next tile (global -> regs) while computing current
        if (kt < 15) {
            k0 = *(const uint4*)&Kg[(size_t)((kt + 1) * 64 + (c0 >> 3)) * HDn + (c0 & 7) * 8];
            k1 = *(const uint4*)&Kg[(size_t)((kt + 1) * 64 + (c1 >> 3)) * HDn + (c1 & 7) * 8];
            v0 = *(const uint4*)&Vg[(size_t)(c0 >> 3) * Sn + (kt + 1) * 64 + (c0 & 7) * 8];
            v1 = *(const uint4*)&Vg[(size_t)(c1 >> 3) * Sn + (kt + 1) * 64 + (c1 & 7) * 8];
        }
        const uint2 m = mbase[(size_t)kt * 256];

#pragma unroll
        for (int mt = 0; mt < 2; ++mt) {
            // ---- S^T tile pair: A = K rows (m=key), B = Q (regs) ----
            float16v s_[2];
#pragma unroll
            for (int jt = 0; jt < 2; ++jt)
#pragma unroll
                for (int r = 0; r < 16; ++r) s_[jt][r] = 0.f;
#pragma unroll
            for (int kp = 0; kp < 4; ++kp) {
                short8 ak = *(const short8*)&Ks[cur][(mt * 32 + col) * 72 + kp * 16 + hi * 8];
                s_[0] = __builtin_amdgcn_mfma_f32_32x32x16_bf16(ak, qf[0][kp], s_[0], 0, 0, 0);
                s_[1] = __builtin_amdgcn_mfma_f32_32x32x16_bf16(ak, qf[1][kp], s_[1], 0, 0, 0);
            }

            // ---- p = bit ? exp(s) : 0 ; pack bf16 pairs ----
            const unsigned mw = (mt == 0) ? m.x : m.y;
            unsigned up[2][8];
#pragma unroll
            for (int jt = 0; jt < 2; ++jt) {
                float p[16];
#pragma unroll
                for (int r = 0; r < 16; ++r) {
                    const float e = __expf(s_[jt][r]);
                    p[r] = ((mw >> (jt * 16 + r)) & 1u) ? e : 0.0f;
                    ls[jt] += p[r];
                }
#pragma unroll
                for (int pr = 0; pr < 8; ++pr)
                    up[jt][pr] = (unsigned)f2bf(p[2 * pr]) | ((unsigned)f2bf(p[2 * pr + 1]) << 16);
            }

            // ---- PV for keys of this mt (kp = 2mt, 2mt+1): B-frags via shfl ----
#pragma unroll
            for (int kh = 0; kh < 2; ++kh) {           // key halves 0-15 / 16-31
                short8 pf[2];
#pragma unroll
                for (int jt = 0; jt < 2; ++jt) {
                    const unsigned a0 = up[jt][kh * 4 + 0], a1 = up[jt][kh * 4 + 1];
                    const unsigned a2 = up[jt][kh * 4 + 2], a3 = up[jt][kh * 4 + 3];
                    const unsigned t0 = (unsigned)__shfl_xor((int)(hi ? a0 : a2), 32, 64);
                    const unsigned t1 = (unsigned)__shfl_xor((int)(hi ? a1 : a3), 32, 64);
                    union { short8 s; unsigned u[4]; } f;
                    f.u[0] = hi ? t0 : a0;
                    f.u[1] = hi ? t1 : a1;
                    f.u[2] = hi ? a2 : t0;
                    f.u[3] = hi ? a3 : t1;
                    pf[jt] = f.s;
                }
                const int kp = mt * 2 + kh;             // key chunk within kt
#pragma unroll
                for (int dt = 0; dt < 2; ++dt) {
                    short8 av = *(const short8*)&Vs[cur][(dt * 32 + col) * 72 + kp * 16 + hi * 8];
                    o_[dt][0] = __builtin_amdgcn_mfma_f32_32x32x16_bf16(av, pf[0], o_[dt][0], 0, 0, 0);
                    o_[dt][1] = __builtin_amdgcn_mfma_f32_32x32x16_bf16(av, pf[1], o_[dt][1], 0, 0, 0);
                }
            }
        }

        if (kt < 15) {
            const int nxt = cur ^ 1;
            *(uint4*)&Ks[nxt][la0] = k0;  *(uint4*)&Ks[nxt][la1] = k1;
            *(uint4*)&Vs[nxt][la0] = v0;  *(uint4*)&Vs[nxt][la1] = v1;
        }
        __syncthreads();
    }

    // ---- epilogue: l = own + partner(lane^32); relu(o/l); float4 stores ----
#pragma unroll
    for (int jt = 0; jt < 2; ++jt) {
        float l = ls[jt] + (float)__shfl_xor((float)ls[jt], 32, 64);
        const float inv = 1.0f / l;
        const int q = qt * 256 + w * 64 + jt * 32 + col;
        float* op = &out[((size_t)b * Sn + q) * Dn + h * 64];
#pragma unroll
        for (int dt = 0; dt < 2; ++dt)
#pragma unroll
            for (int rg = 0; rg < 4; ++rg) {
                const int d = dt * 32 + rg * 8 + hi * 4;
                float4 o4;
                o4.x = fmaxf(o_[dt][jt][rg * 4 + 0] * inv, 0.0f);
                o4.y = fmaxf(o_[dt][jt][rg * 4 + 1] * inv, 0.0f);
                o4.z = fmaxf(o_[dt][jt][rg * 4 + 2] * inv, 0.0f);
                o4.w = fmaxf(o_[dt][jt][rg * 4 + 3] * inv, 0.0f);
                *(float4*)&op[d] = o4;
            }
    }
}

extern "C" void kernel_launch(void* const* d_in, const int* in_sizes, int n_in,
                              void* d_out, int out_size, void* d_ws, size_t ws_size,
                              hipStream_t stream)
{
    const float* x   = (const float*)d_in[0];
    const float* adj = (const float*)d_in[1];
    const float* Wq  = (const float*)d_in[2];
    const float* bq  = (const float*)d_in[3];
    const float* Wk  = (const float*)d_in[4];
    const float* bk  = (const float*)d_in[5];
    const float* Wv  = (const float*)d_in[6];
    const float* bv  = (const float*)d_in[7];
    float* out = (float*)d_out;

    // ws (ushort): xb | Wt | Qb | Kb | Vb, then Mb (uint2, 8B-aligned)  ~= 41.8 MB
    ushort* xb = (ushort*)d_ws;
    ushort* Wt = xb + (size_t)Bn * Sn * Dn;
    ushort* Qb = Wt + (size_t)3 * Dn * Dn;
    ushort* Kb = Qb + (size_t)Bn * Hn * Sn * HDn;
    ushort* Vb = Kb + (size_t)Bn * Hn * Sn * HDn;
    uint2*  Mb = (uint2*)(Vb + (size_t)Bn * Hn * Sn * HDn);

    convert_x<<<dim3((Bn * Sn * Dn) / (256 * 8)), 256, 0, stream>>>(x, xb);
    transpose_w<<<dim3(16, 16, 3), 256, 0, stream>>>(Wq, Wk, Wv, Wt);
    build_mask<<<dim3((Bn * 4 * 16 * 4 * 64) / 256), 256, 0, stream>>>(adj, Mb);

    qkv_gemm<<<dim3(Dn / 128, (Bn * Sn) / 128, 3), 256, 0, stream>>>(
        xb, Wt, bq, bk, bv, Qb, Kb, Vb);

    attn_mfma<<<dim3(Sn / 256, Hn, Bn), 256, 0, stream>>>(Qb, Kb, Vb, Mb, out);

    hipMemcpyAsync(out + (size_t)Bn * Sn * Dn, adj,
                   (size_t)Bn * Sn * Sn * sizeof(float),
                   hipMemcpyDeviceToDevice, stream);
}

// Round 7
// 191.009 us; speedup vs baseline: 3.7090x; 1.0077x over previous
//
#include <hip/hip_runtime.h>

constexpr int Bn  = 4;
constexpr int Sn  = 1024;
constexpr int Dn  = 1024;
constexpr int Hn  = 16;
constexpr int HDn = 64;

using short8   = __attribute__((ext_vector_type(8))) short;
using float4v  = __attribute__((ext_vector_type(4))) float;
using float16v = __attribute__((ext_vector_type(16))) float;

__device__ __forceinline__ ushort f2bf(float f) {
    union { float f; unsigned u; } v; v.f = f;
    unsigned r = v.u + 0x7fff + ((v.u >> 16) & 1);   // RNE
    return (ushort)(r >> 16);
}

__device__ __forceinline__ void gload16(const void* g, void* l) {
    __builtin_amdgcn_global_load_lds(
        (const __attribute__((address_space(1))) void*)g,
        (__attribute__((address_space(3))) void*)l, 16, 0, 0);
}

// ---------------------------------------------------------------------------
// prep (fused): [0,2048) convert_x | [2048,2816) transpose_w | [2816,3328) build_mask
// build_mask: per-pair halfword masks (0xFFFF = keep) in PV-pack fragment order.
//   group = ((b*8+qt)*16+kt)*4+w ; per lane 16 words [mt(2)][pr(8)] at Mb+rid*16.
//   pair pr covers keys mt*32 + 8*(pr>>1) + 2*(pr&1) + 4*hi + {0,1}; q = qt*128+w*32+col.
// ---------------------------------------------------------------------------
__global__ __launch_bounds__(256) void prep(
    const float* __restrict__ x,
    const float* __restrict__ Wq, const float* __restrict__ Wk,
    const float* __restrict__ Wv, const float* __restrict__ adj,
    ushort* __restrict__ xb, ushort* __restrict__ Wt, uint* __restrict__ Mb)
{
    const int bx  = blockIdx.x;
    const int tid = threadIdx.x;
    __shared__ __align__(16) ushort T[64 * 72];

    if (bx < 2048) {
        // ---- convert_x ----
        const size_t i = ((size_t)bx * 256 + tid) * 8;
        float4 a = *(const float4*)&x[i];
        float4 b = *(const float4*)&x[i + 4];
        ushort o[8] = {f2bf(a.x), f2bf(a.y), f2bf(a.z), f2bf(a.w),
                       f2bf(b.x), f2bf(b.y), f2bf(b.z), f2bf(b.w)};
        *(uint4*)&xb[i] = *(const uint4*)o;
    } else if (bx < 2816) {
        // ---- transpose_w: W (KxN fp32) -> Wt (NxK bf16) ----
        const int idx = bx - 2048;
        const int which = idx >> 8, rem = idx & 255;
        const float* __restrict__ W = (which == 0) ? Wq : (which == 1) ? Wk : Wv;
        ushort* __restrict__ O = Wt + (size_t)which * Dn * Dn;
        const int k0 = (rem & 15) * 64, n0 = (rem >> 4) * 64;

        const int kl = tid >> 4, nl = (tid & 15) * 4;
#pragma unroll
        for (int p = 0; p < 4; ++p) {
            float4 w4 = *(const float4*)&W[(size_t)(k0 + p * 16 + kl) * Dn + n0 + nl];
            T[(nl + 0) * 72 + p * 16 + kl] = f2bf(w4.x);
            T[(nl + 1) * 72 + p * 16 + kl] = f2bf(w4.y);
            T[(nl + 2) * 72 + p * 16 + kl] = f2bf(w4.z);
            T[(nl + 3) * 72 + p * 16 + kl] = f2bf(w4.w);
        }
        __syncthreads();
        const int nr = tid >> 2, kc = (tid & 3) * 16;
        uint4 u0 = *(const uint4*)&T[nr * 72 + kc];
        uint4 u1 = *(const uint4*)&T[nr * 72 + kc + 8];
        *(uint4*)&O[(size_t)(n0 + nr) * Dn + k0 + kc]     = u0;
        *(uint4*)&O[(size_t)(n0 + nr) * Dn + k0 + kc + 8] = u1;
    } else {
        // ---- build_mask ----
        const int rid  = (bx - 2816) * 256 + tid;
        const int lane = rid & 63;
        const int w    = (rid >> 6) & 3;
        const int kt   = (rid >> 8) & 15;
        const int qt   = (rid >> 12) & 7;
        const int b    = rid >> 15;
        const int col  = lane & 31, hi = lane >> 5;
        const int q    = qt * 128 + w * 32 + col;
        const float* arow = adj + ((size_t)b * Sn + q) * Sn + kt * 64;

        uint words[16];
#pragma unroll
        for (int mt = 0; mt < 2; ++mt)
#pragma unroll
            for (int pr = 0; pr < 8; ++pr) {
                const int r0 = 2 * pr;
                const int k0l = mt * 32 + (r0 & 3) + 8 * (r0 >> 2) + 4 * hi;
                float2 a = *(const float2*)&arow[k0l];   // k0l even, k1l = k0l+1
                words[mt * 8 + pr] = (a.x >= 0.5f ? 0x0000FFFFu : 0u) |
                                     (a.y >= 0.5f ? 0xFFFF0000u : 0u);
            }
        uint* dst = Mb + (size_t)rid * 16;
#pragma unroll
        for (int c = 0; c < 4; ++c)
            *(uint4*)&dst[c * 4] = make_uint4(words[c*4], words[c*4+1], words[c*4+2], words[c*4+3]);
    }
}

// ---------------------------------------------------------------------------
// bf16 MFMA GEMM: Q pre-scaled by 0.125*log2(e); Q/K -> [B,H,S,HD], V -> [B,H,HD,S]
// ---------------------------------------------------------------------------
__global__ __launch_bounds__(256) void qkv_gemm(
    const ushort* __restrict__ xb, const ushort* __restrict__ Wt,
    const float* __restrict__ bq, const float* __restrict__ bk,
    const float* __restrict__ bv,
    ushort* __restrict__ Qb, ushort* __restrict__ Kb, ushort* __restrict__ Vb)
{
    const int which = blockIdx.z;
    const ushort* __restrict__ Bw   = Wt + (size_t)which * Dn * Dn;
    const float* __restrict__  bias = (which == 0) ? bq : (which == 1) ? bk : bv;
    ushort* __restrict__       Out  = (which == 0) ? Qb : (which == 1) ? Kb : Vb;
    const float scale = (which == 0) ? 0.18033688011112042f : 1.0f;  // 0.125*log2(e)

    const int n0   = blockIdx.x * 128;
    const int m0   = blockIdx.y * 128;
    const int tid  = threadIdx.x;
    const int wave = tid >> 6;
    const int lane = tid & 63;
    const int wm   = wave >> 1;
    const int wn   = wave & 1;

    __shared__ __align__(16) ushort As[128 * 32];
    __shared__ __align__(16) ushort Bs[128 * 32];

    const int L0 = wave * 64 + lane;
    const int r0s = L0 >> 2, c0s = (L0 & 3) * 8;
    const int L1 = L0 + 256;
    const int r1s = L1 >> 2, c1s = (L1 & 3) * 8;

    const ushort* pA0 = &xb[(size_t)(m0 + r0s) * Dn + c0s];
    const ushort* pA1 = &xb[(size_t)(m0 + r1s) * Dn + c1s];
    const ushort* pB0 = &Bw[(size_t)(n0 + r0s) * Dn + c0s];
    const ushort* pB1 = &Bw[(size_t)(n0 + r1s) * Dn + c1s];

    char* ldsA0 = (char*)As + wave * 1024;
    char* ldsA1 = (char*)As + wave * 1024 + 4096;
    char* ldsB0 = (char*)Bs + wave * 1024;
    char* ldsB1 = (char*)Bs + wave * 1024 + 4096;

    const int mlane = lane & 15;
    const int kg    = (lane >> 4) * 8;

    float4v acc[4][4];
    const float4v z4 = {0.f, 0.f, 0.f, 0.f};
#pragma unroll
    for (int i = 0; i < 4; ++i)
#pragma unroll
        for (int j = 0; j < 4; ++j) acc[i][j] = z4;

    for (int k0 = 0; k0 < Dn; k0 += 32) {
        __syncthreads();
        gload16(pA0, ldsA0);
        gload16(pA1, ldsA1);
        gload16(pB0, ldsB0);
        gload16(pB1, ldsB1);
        pA0 += 32; pA1 += 32; pB0 += 32; pB1 += 32;
        __syncthreads();

        short8 af[4], bf[4];
#pragma unroll
        for (int i = 0; i < 4; ++i)
            af[i] = *(const short8*)&As[(wm * 64 + i * 16 + mlane) * 32 + kg];
#pragma unroll
        for (int j = 0; j < 4; ++j)
            bf[j] = *(const short8*)&Bs[(wn * 64 + j * 16 + mlane) * 32 + kg];
#pragma unroll
        for (int i = 0; i < 4; ++i)
#pragma unroll
            for (int j = 0; j < 4; ++j)
                acc[i][j] = __builtin_amdgcn_mfma_f32_16x16x32_bf16(af[i], bf[j], acc[i][j], 0, 0, 0);
    }

    const int rb  = (lane >> 4) * 4;
    const int col = lane & 15;
#pragma unroll
    for (int j = 0; j < 4; ++j) {
        const int n  = n0 + wn * 64 + j * 16 + col;
        const float bias_n = bias[n];
        const int h  = n >> 6;
        const int hd = n & 63;
#pragma unroll
        for (int i = 0; i < 4; ++i) {
#pragma unroll
            for (int r = 0; r < 4; ++r) {
                const int m = m0 + wm * 64 + i * 16 + rb + r;
                const int b = m >> 10;
                const int s = m & 1023;
                size_t addr;
                if (which == 2)
                    addr = (((size_t)(b * Hn + h)) * HDn + hd) * Sn + s;   // V transposed
                else
                    addr = (((size_t)(b * Hn + h)) * Sn + s) * HDn + hd;
                Out[addr] = f2bf((acc[i][j][r] + bias_n) * scale);
            }
        }
    }
}

// ---------------------------------------------------------------------------
// MFMA flash attention, 32x32x16, P in registers (shfl C->B), pair-masks,
// exp2 softmax with deferred row sum. Block = 128 q of one (b,h): 4 waves x 32 q.
// grid (8,16,4) = 512 blocks = 2 blocks/CU. LDS 36 KB, stride 72, double-buffered.
// ---------------------------------------------------------------------------
__global__ __launch_bounds__(256, 2) void attn_mfma(
    const ushort* __restrict__ Q, const ushort* __restrict__ K,
    const ushort* __restrict__ Vt, const uint* __restrict__ Mw,
    float* __restrict__ out)
{
    const int qt = blockIdx.x, h = blockIdx.y, b = blockIdx.z;
    const int tid  = threadIdx.x;
    const int w    = tid >> 6, lane = tid & 63;
    const int col  = lane & 31, hi = lane >> 5;

    const size_t hb = ((size_t)(b * Hn + h)) * Sn * HDn;
    const ushort* Kg = K + hb;          // [key][dim]
    const ushort* Vg = Vt + hb;         // [dim][key]

    __shared__ __align__(16) ushort Ks[2][64 * 72];
    __shared__ __align__(16) ushort Vs[2][64 * 72];

    // Q B-frags (registers, all kt): B[k=dim][n=q], n=col, k=kp*16+hi*8+i
    short8 qf[4];
#pragma unroll
    for (int kp = 0; kp < 4; ++kp)
        qf[kp] = *(const short8*)&Q[hb +
            (size_t)(qt * 128 + w * 32 + col) * HDn + kp * 16 + hi * 8];

    float16v o_[2];   // [dim-tile]
#pragma unroll
    for (int dt = 0; dt < 2; ++dt)
#pragma unroll
        for (int r = 0; r < 16; ++r) o_[dt][r] = 0.f;
    float ls = 0.f;

    // staging: chunk c -> row c>>3, 8-elem chunk (c&7); lds = row*72 + (c&7)*8
    const int c0 = tid, c1 = tid + 256;
    const int la0 = (c0 >> 3) * 72 + (c0 & 7) * 8;
    const int la1 = (c1 >> 3) * 72 + (c1 & 7) * 8;

    uint4 k0 = *(const uint4*)&Kg[(size_t)(c0 >> 3) * HDn + (c0 & 7) * 8];
    uint4 k1 = *(const uint4*)&Kg[(size_t)(c1 >> 3) * HDn + (c1 & 7) * 8];
    uint4 v0 = *(const uint4*)&Vg[(size_t)(c0 >> 3) * Sn + (c0 & 7) * 8];
    uint4 v1 = *(const uint4*)&Vg[(size_t)(c1 >> 3) * Sn + (c1 & 7) * 8];
    *(uint4*)&Ks[0][la0] = k0;  *(uint4*)&Ks[0][la1] = k1;
    *(uint4*)&Vs[0][la0] = v0;  *(uint4*)&Vs[0][la1] = v1;
    __syncthreads();

    // mask: group = ((b*8+qt)*16+kt)*4+w ; lane base = group*1024 + lane*16
    const uint* mbase = Mw + ((size_t)((b * 8 + qt) * 16) * 4 + w) * 1024 + lane * 16;

    for (int kt = 0; kt < 16; ++kt) {
        const int cur = kt & 1;
        if (kt < 15) {
            k0 = *(const uint4*)&Kg[(size_t)((kt + 1) * 64 + (c0 >> 3)) * HDn + (c0 & 7) * 8];
            k1 = *(const uint4*)&Kg[(size_t)((kt + 1) * 64 + (c1 >> 3)) * HDn + (c1 & 7) * 8];
            v0 = *(const uint4*)&Vg[(size_t)(c0 >> 3) * Sn + (kt + 1) * 64 + (c0 & 7) * 8];
            v1 = *(const uint4*)&Vg[(size_t)(c1 >> 3) * Sn + (kt + 1) * 64 + (c1 & 7) * 8];
        }
        const uint* mp = mbase + (size_t)kt * 4096;
        uint4 mk4[4];
        mk4[0] = *(const uint4*)(mp);
        mk4[1] = *(const uint4*)(mp + 4);
        mk4[2] = *(const uint4*)(mp + 8);
        mk4[3] = *(const uint4*)(mp + 12);
        const uint* mka = (const uint*)mk4;   // [mt*8 + pr]

#pragma unroll
        for (int mt = 0; mt < 2; ++mt) {
            // ---- S^T tile: A = K rows (m=key), B = Q (regs); C holds S^T*log2e ----
            float16v s_;
#pragma unroll
            for (int r = 0; r < 16; ++r) s_[r] = 0.f;
#pragma unroll
            for (int kp = 0; kp < 4; ++kp) {
                short8 ak = *(const short8*)&Ks[cur][(mt * 32 + col) * 72 + kp * 16 + hi * 8];
                s_ = __builtin_amdgcn_mfma_f32_32x32x16_bf16(ak, qf[kp], s_, 0, 0, 0);
            }

            // ---- p = 2^s ; round-to-bf16 pack (perm) ; mask (and) ; sum trunc ----
            unsigned up[8];
#pragma unroll
            for (int pr = 0; pr < 8; ++pr) {
                const unsigned e0 = __float_as_uint(exp2f(s_[2 * pr]))     + 0x8000u;
                const unsigned e1 = __float_as_uint(exp2f(s_[2 * pr + 1])) + 0x8000u;
                const unsigned u  = __builtin_amdgcn_perm(e1, e0, 0x07060302u) & mka[mt * 8 + pr];
                up[pr] = u;
                ls += __uint_as_float(u << 16) + __uint_as_float(u & 0xffff0000u);
            }

            // ---- PV: B-frags via shfl_xor(32) C->B transform ----
#pragma unroll
            for (int kh = 0; kh < 2; ++kh) {
                const unsigned a0 = up[kh * 4 + 0], a1 = up[kh * 4 + 1];
                const unsigned a2 = up[kh * 4 + 2], a3 = up[kh * 4 + 3];
                const unsigned t0 = (unsigned)__shfl_xor((int)(hi ? a0 : a2), 32, 64);
                const unsigned t1 = (unsigned)__shfl_xor((int)(hi ? a1 : a3), 32, 64);
                union { short8 s; unsigned u[4]; } f;
                f.u[0] = hi ? t0 : a0;
                f.u[1] = hi ? t1 : a1;
                f.u[2] = hi ? a2 : t0;
                f.u[3] = hi ? a3 : t1;
                const int kp = mt * 2 + kh;
#pragma unroll
                for (int dt = 0; dt < 2; ++dt) {
                    short8 av = *(const short8*)&Vs[cur][(dt * 32 + col) * 72 + kp * 16 + hi * 8];
                    o_[dt] = __builtin_amdgcn_mfma_f32_32x32x16_bf16(av, f.s, o_[dt], 0, 0, 0);
                }
            }
        }

        if (kt < 15) {
            const int nxt = cur ^ 1;
            *(uint4*)&Ks[nxt][la0] = k0;  *(uint4*)&Ks[nxt][la1] = k1;
            *(uint4*)&Vs[nxt][la0] = v0;  *(uint4*)&Vs[nxt][la1] = v1;
        }
        __syncthreads();
    }

    // ---- epilogue: l = own + partner(lane^32); relu(o/l); float4 stores ----
    float l = ls + (float)__shfl_xor((float)ls, 32, 64);
    const float inv = 1.0f / l;
    const int q = qt * 128 + w * 32 + col;
    float* op = &out[((size_t)b * Sn + q) * Dn + h * 64];
#pragma unroll
    for (int dt = 0; dt < 2; ++dt)
#pragma unroll
        for (int rg = 0; rg < 4; ++rg) {
            const int d = dt * 32 + rg * 8 + hi * 4;
            float4 o4;
            o4.x = fmaxf(o_[dt][rg * 4 + 0] * inv, 0.0f);
            o4.y = fmaxf(o_[dt][rg * 4 + 1] * inv, 0.0f);
            o4.z = fmaxf(o_[dt][rg * 4 + 2] * inv, 0.0f);
            o4.w = fmaxf(o_[dt][rg * 4 + 3] * inv, 0.0f);
            *(float4*)&op[d] = o4;
        }
}

extern "C" void kernel_launch(void* const* d_in, const int* in_sizes, int n_in,
                              void* d_out, int out_size, void* d_ws, size_t ws_size,
                              hipStream_t stream)
{
    const float* x   = (const float*)d_in[0];
    const float* adj = (const float*)d_in[1];
    const float* Wq  = (const float*)d_in[2];
    const float* bq  = (const float*)d_in[3];
    const float* Wk  = (const float*)d_in[4];
    const float* bk  = (const float*)d_in[5];
    const float* Wv  = (const float*)d_in[6];
    const float* bv  = (const float*)d_in[7];
    float* out = (float*)d_out;

    // ws (ushort): xb[4.19M] | Wt[3.15M] | Qb | Kb | Vb [4.19M ea] then Mb (uint, 8 MB)
    ushort* xb = (ushort*)d_ws;
    ushort* Wt = xb + (size_t)Bn * Sn * Dn;
    ushort* Qb = Wt + (size_t)3 * Dn * Dn;
    ushort* Kb = Qb + (size_t)Bn * Hn * Sn * HDn;
    ushort* Vb = Kb + (size_t)Bn * Hn * Sn * HDn;
    uint*   Mb = (uint*)(Vb + (size_t)Bn * Hn * Sn * HDn);

    prep<<<dim3(3328), 256, 0, stream>>>(x, Wq, Wk, Wv, adj, xb, Wt, Mb);

    qkv_gemm<<<dim3(Dn / 128, (Bn * Sn) / 128, 3), 256, 0, stream>>>(
        xb, Wt, bq, bk, bv, Qb, Kb, Vb);

    attn_mfma<<<dim3(8, Hn, Bn), 256, 0, stream>>>(Qb, Kb, Vb, Mb, out);

    hipMemcpyAsync(out + (size_t)Bn * Sn * Dn, adj,
                   (size_t)Bn * Sn * Sn * sizeof(float),
                   hipMemcpyDeviceToDevice, stream);
}